// Round 7
// baseline (613.636 us; speedup 1.0000x reference)
//
#include <hip/hip_runtime.h>
#include <cstdint>
#include <cstddef>

#define BN 8
#define NN 16384
#define DD 256
#define KK 16
#define NITER 5
#define EPSV 1e-8f
#define TILE 64
#define XPAD 257   // f32 row stride in LDS: 257%32==1 -> conflict-free b32

__device__ __forceinline__ float frcp(float x){ return __builtin_amdgcn_rcpf(x); }
__device__ __forceinline__ float rdlane(float v, int l){
  return __int_as_float(__builtin_amdgcn_readlane(__float_as_int(v), l));
}
__device__ __forceinline__ float wmax(float v){
  #pragma unroll
  for (int m = 32; m >= 1; m >>= 1) v = fmaxf(v, __shfl_xor(v, m, 64));
  return v;
}
__device__ __forceinline__ float wsum(float v){
  #pragma unroll
  for (int m = 32; m >= 1; m >>= 1) v += __shfl_xor(v, m, 64);
  return v;
}

// ---------------- row stats: per-row max and 1/sum(exp(x-max)) -------------
__global__ __launch_bounds__(256) void k_rowstats(const float* __restrict__ x,
                                                  float2* __restrict__ stats){
  int row  = blockIdx.x * 4 + (threadIdx.x >> 6);
  int lane = threadIdx.x & 63;
  const float4* xr = (const float4*)(x + (size_t)row * DD);
  float4 v = xr[lane];
  float m = wmax(fmaxf(fmaxf(v.x, v.y), fmaxf(v.z, v.w)));
  float s = wsum(__expf(v.x - m) + __expf(v.y - m) + __expf(v.z - m) + __expf(v.w - m));
  if (lane == 0) stats[row] = make_float2(m, frcp(s));
}

// ------------- init: logqT[b][d][k] = log_softmax(slot_logits), logpi0 -----
__global__ __launch_bounds__(256) void k_initparams(const float* __restrict__ slot_logits,
                                                    const float* __restrict__ mix,
                                                    float* __restrict__ logqT,
                                                    float* __restrict__ logpi){
  int w    = blockIdx.x * 4 + (threadIdx.x >> 6);   // w = b*K + k, 0..127
  int lane = threadIdx.x & 63;
  int b = w >> 4, k = w & 15;
  const float4* sl = (const float4*)(slot_logits + (size_t)k * DD);
  float4 t = sl[lane];
  float m = wmax(fmaxf(fmaxf(t.x, t.y), fmaxf(t.z, t.w)));
  float s = wsum(__expf(t.x - m) + __expf(t.y - m) + __expf(t.z - m) + __expf(t.w - m));
  float L = m + __logf(s);
  float* dq = logqT + (size_t)b * DD * KK;
  int d0 = lane * 4;
  dq[(d0+0)*KK + k] = t.x - L;
  dq[(d0+1)*KK + k] = t.y - L;
  dq[(d0+2)*KK + k] = t.z - L;
  dq[(d0+3)*KK + k] = t.w - L;
  if (lane == 0) logpi[w] = __logf(mix[k] + EPSV);
}

// ---------------- staging: 64-row x-tile -> LDS ----------------------------
// Each wave stages its 16 rows x 4 quarters = 64 width-4 global_load_lds
// (r6 bug: only 16 -> 3/4 of tile unstaged -> NaN).
__device__ __forceinline__ void stage_tile(const float* __restrict__ xb, int n0,
                                           float* xl, int wave, int lane){
#if defined(__has_builtin) && __has_builtin(__builtin_amdgcn_global_load_lds)
  #pragma unroll
  for (int i = 0; i < 64; ++i){
    int r = (wave << 4) + (i >> 2);     // 16 rows per wave
    int q = i & 3;                      // 4 quarters of 64 floats
    const float* gp = xb + (size_t)(n0 + r) * DD + q * 64 + lane;
    float* lp = &xl[r * XPAD + q * 64];    // wave-uniform base; HW adds lane*4
    __builtin_amdgcn_global_load_lds(
        (const __attribute__((address_space(1))) unsigned int*)gp,
        (__attribute__((address_space(3))) unsigned int*)lp, 4, 0, 0);
  }
#else
  #pragma unroll
  for (int i = 0; i < 64; ++i){
    int r = (wave << 4) + (i >> 2);
    int q = i & 3;
    xl[r * XPAD + q * 64 + lane] = xb[(size_t)(n0 + r) * DD + q * 64 + lane];
  }
#endif
}

// -------- fused EM iteration: lane-parallel rows, no shuffle chains --------
__global__ __launch_bounds__(256, 2) void k_em2(const float* __restrict__ x,
                                                const float2* __restrict__ stats,
                                                const float* __restrict__ logqT,
                                                const float* __restrict__ logpi,
                                                float* __restrict__ pnum,
                                                float* __restrict__ ppi, int G){
  __shared__ float xl[TILE * XPAD];        // 65792 B
  __shared__ float plog[TILE * 17];        //  4352 B

  const int b = blockIdx.y, g = blockIdx.x;
  const int tid  = threadIdx.x;
  const int wave = __builtin_amdgcn_readfirstlane(tid >> 6);
  const int lane = tid & 63;
  const int rows_pb = NN / G;
  const int tiles   = rows_pb / TILE;
  const int n00     = g * rows_pb;

  const float*  xb  = x + (size_t)b * NN * DD;
  const float2* stb = stats + (size_t)b * NN;
  const float*  lq  = logqT + (size_t)b * DD * KK;

  float lpik[KK];
  #pragma unroll
  for (int k = 0; k < KK; ++k) lpik[k] = logpi[b * KK + k];

  float acc[KK][4];
  #pragma unroll
  for (int k = 0; k < KK; ++k){ acc[k][0]=0.f; acc[k][1]=0.f; acc[k][2]=0.f; acc[k][3]=0.f; }
  float piacc[KK];
  #pragma unroll
  for (int k = 0; k < KK; ++k) piacc[k] = 0.f;

  // prologue: stage tile 0, zero plog
  stage_tile(xb, n00, xl, wave, lane);
  for (int i = tid; i < TILE * 17; i += 256) plog[i] = 0.f;

  for (int t = 0; t < tiles; ++t){
    const int n0 = n00 + t * TILE;
    asm volatile("s_waitcnt vmcnt(0)" ::: "memory");
    __syncthreads();                           // bar1: xl ready, plog zeroed

    float2 st = stb[n0 + lane];                // this lane's row stats

    // ---- dot: row = lane, d in [wave*64, wave*64+64) -----------------
    float part[KK];
    #pragma unroll
    for (int k = 0; k < KK; ++k) part[k] = 0.f;
    const int dbase = wave * 64;
    const float* xrow = &xl[lane * XPAD + dbase];
    #pragma unroll 2
    for (int jc = 0; jc < 16; ++jc){
      float p0 = __expf(xrow[jc*4+0] - st.x);
      float p1 = __expf(xrow[jc*4+1] - st.x);
      float p2 = __expf(xrow[jc*4+2] - st.x);
      float p3 = __expf(xrow[jc*4+3] - st.x);
      const float* lq0 = &lq[(dbase + jc*4) * KK];   // wave-uniform -> s_load
      #pragma unroll
      for (int k = 0; k < KK; ++k){
        part[k] = fmaf(p0, lq0[k],        part[k]);
        part[k] = fmaf(p1, lq0[KK + k],   part[k]);
        part[k] = fmaf(p2, lq0[2*KK + k], part[k]);
        part[k] = fmaf(p3, lq0[3*KK + k], part[k]);
      }
    }
    #pragma unroll
    for (int k = 0; k < KK; ++k) atomicAdd(&plog[lane * 17 + k], part[k]);
    __syncthreads();                           // bar2: logits complete

    // ---- softmax over 16 slots, fully in-register per lane -----------
    float lg[KK];
    #pragma unroll
    for (int k = 0; k < KK; ++k) lg[k] = fmaf(plog[lane * 17 + k], st.y, lpik[k]);
    float m8[8], m4[4], m2[2];
    #pragma unroll
    for (int i = 0; i < 8; ++i) m8[i] = fmaxf(lg[i], lg[i+8]);
    #pragma unroll
    for (int i = 0; i < 4; ++i) m4[i] = fmaxf(m8[i], m8[i+4]);
    m2[0] = fmaxf(m4[0], m4[2]); m2[1] = fmaxf(m4[1], m4[3]);
    float mx = fmaxf(m2[0], m2[1]);
    float ga[KK];
    #pragma unroll
    for (int k = 0; k < KK; ++k) ga[k] = __expf(lg[k] - mx);
    float s8[8], s4[4], s2[2];
    #pragma unroll
    for (int i = 0; i < 8; ++i) s8[i] = ga[i] + ga[i+8];
    #pragma unroll
    for (int i = 0; i < 4; ++i) s4[i] = s8[i] + s8[i+4];
    s2[0] = s4[0] + s4[2]; s2[1] = s4[1] + s4[3];
    float inv = frcp(s2[0] + s2[1]);
    #pragma unroll
    for (int k = 0; k < KK; ++k){ ga[k] *= inv; piacc[k] += ga[k]; }

    // ---- accum: wave handles rows [16w, 16w+16); lane owns dims l+64j -
    #pragma unroll 2
    for (int rr = 0; rr < 16; ++rr){
      const int r = wave * 16 + rr;
      const float* xr2 = &xl[r * XPAD + lane];
      float xv0 = xr2[0], xv1 = xr2[64], xv2 = xr2[128], xv3 = xr2[192];
      #pragma unroll
      for (int k = 0; k < KK; ++k){
        float gk = rdlane(ga[k], r);           // row r's gamma lives in lane r
        acc[k][0] = fmaf(gk, xv0, acc[k][0]);
        acc[k][1] = fmaf(gk, xv1, acc[k][1]);
        acc[k][2] = fmaf(gk, xv2, acc[k][2]);
        acc[k][3] = fmaf(gk, xv3, acc[k][3]);
      }
    }
    __syncthreads();                           // bar3: done reading xl/plog
    if (t + 1 < tiles) stage_tile(xb, n0 + TILE, xl, wave, lane);
    for (int i = tid; i < TILE * 17; i += 256) plog[i] = 0.f;
  }

  // ---- epilogue: cross-wave reduce acc via xl scratch ------------------
  float* sred = xl;                            // reuse (4160 floats needed)
  if (wave == 0){
    #pragma unroll
    for (int k = 0; k < KK; ++k)
      #pragma unroll
      for (int j = 0; j < 4; ++j) sred[(k*4+j)*65 + lane] = acc[k][j];
  }
  __syncthreads();
  for (int w = 1; w < 4; ++w){
    if (wave == w){
      #pragma unroll
      for (int k = 0; k < KK; ++k)
        #pragma unroll
        for (int j = 0; j < 4; ++j) sred[(k*4+j)*65 + lane] += acc[k][j];
    }
    __syncthreads();
  }
  float* dst = pnum + (size_t)(b * G + g) * KK * DD;
  for (int i = tid; i < KK * DD; i += 256){
    int k = i >> 8, d = i & 255, j = d >> 6, l = d & 63;
    dst[i] = sred[(k*4+j)*65 + l];
  }
  if (wave == 0){
    #pragma unroll
    for (int k = 0; k < KK; ++k){
      float v = wsum(piacc[k]);                // all waves' piacc identical
      if (lane == 0) ppi[(size_t)(b * G + g) * KK + k] = v;
    }
  }
}

// ---------------- reduce partials -> theta, logqT, log_pi ------------------
__global__ __launch_bounds__(64) void k_reduce(const float* __restrict__ pnum,
                                               const float* __restrict__ ppi,
                                               float* __restrict__ theta,
                                               float* __restrict__ logqT,
                                               float* __restrict__ logpi, int G){
  int w = blockIdx.x;              // b*K + k
  int lane = threadIdx.x;
  int b = w >> 4, k = w & 15;
  float4 sum = make_float4(0.f, 0.f, 0.f, 0.f);
  const float4* base = (const float4*)pnum + ((size_t)b * G * KK + k) * (DD/4) + lane;
  #pragma unroll 4
  for (int g = 0; g < G; ++g){
    float4 t = base[(size_t)g * KK * (DD/4)];
    sum.x += t.x; sum.y += t.y; sum.z += t.z; sum.w += t.w;
  }
  float ps = 0.f;
  for (int g = lane; g < G; g += 64) ps += ppi[((size_t)b * G + g) * KK + k];
  ps = wsum(ps);
  float inv = frcp(ps + EPSV);
  float4 th = make_float4(sum.x * inv, sum.y * inv, sum.z * inv, sum.w * inv);
  ((float4*)(theta + (size_t)w * DD))[lane] = th;
  float m = wmax(fmaxf(fmaxf(th.x, th.y), fmaxf(th.z, th.w)));
  float s = wsum(__expf(th.x - m) + __expf(th.y - m) + __expf(th.z - m) + __expf(th.w - m));
  float L = m + __logf(s);
  float* dq = logqT + (size_t)b * DD * KK;
  int d0 = lane * 4;
  dq[(d0+0)*KK + k] = th.x - L;
  dq[(d0+1)*KK + k] = th.y - L;
  dq[(d0+2)*KK + k] = th.z - L;
  dq[(d0+3)*KK + k] = th.w - L;
  if (lane == 0) logpi[w] = __logf(ps * (1.0f / NN) + EPSV);
}

// ---------------- threefry2x32-20 core (general key) -----------------------
__device__ __forceinline__ uint32_t rotl32(uint32_t x, int r){ return (x << r) | (x >> (32 - r)); }
__device__ __forceinline__ void tf2x32(uint32_t k0, uint32_t k1, uint32_t c0, uint32_t c1,
                                       uint32_t& o0, uint32_t& o1){
  uint32_t ks0 = k0, ks1 = k1, ks2 = 0x1BD11BDAu ^ k0 ^ k1;
  uint32_t x0 = c0 + ks0, x1 = c1 + ks1;
  #define RND(r) { x0 += x1; x1 = rotl32(x1, r); x1 ^= x0; }
  RND(13) RND(15) RND(26) RND(6)   x0 += ks1; x1 += ks2 + 1u;
  RND(17) RND(29) RND(16) RND(24)  x0 += ks2; x1 += ks0 + 2u;
  RND(13) RND(15) RND(26) RND(6)   x0 += ks0; x1 += ks1 + 3u;
  RND(17) RND(29) RND(16) RND(24)  x0 += ks1; x1 += ks2 + 4u;
  RND(13) RND(15) RND(26) RND(6)   x0 += ks2; x1 += ks0 + 5u;
  #undef RND
  o0 = x0; o1 = x1;
}

// ---------------- final: gumbel (partitionable XOR-fold, VERIFIED) ---------
__global__ __launch_bounds__(256) void k_final(const float* __restrict__ theta,
                                               float* __restrict__ out){
  int w    = blockIdx.x * 4 + (threadIdx.x >> 6);   // b*K + k
  int lane = threadIdx.x & 63;
  float4 th = ((const float4*)(theta + (size_t)w * DD))[lane];
  int i0 = w * DD + lane * 4;
  float gv[4];
  #pragma unroll
  for (int j = 0; j < 4; ++j){
    uint32_t i = (uint32_t)(i0 + j);
    uint32_t o0, o1;
    tf2x32(0u, 1u, 0u, i, o0, o1);      // ctr = (hi=0, lo=i)
    uint32_t bits = o0 ^ o1;            // partitionable <=32-bit: bits1 ^ bits2
    float f = __uint_as_float((bits >> 9) | 0x3f800000u) - 1.0f;
    const float TINY = 1.17549435e-38f;
    float u = fmaxf(f + TINY, TINY);
    gv[j] = -logf(-logf(u));
  }
  float4 y = make_float4(th.x + gv[0], th.y + gv[1], th.z + gv[2], th.w + gv[3]);
  float m = wmax(fmaxf(fmaxf(y.x, y.y), fmaxf(y.z, y.w)));
  float4 e = make_float4(__expf(y.x - m), __expf(y.y - m), __expf(y.z - m), __expf(y.w - m));
  float s = wsum(e.x + e.y + e.z + e.w);
  float inv = 1.0f / s;
  ((float4*)(out + (size_t)w * DD))[lane] =
      make_float4(e.x * inv, e.y * inv, e.z * inv, e.w * inv);
}

__global__ __launch_bounds__(256) void k_fill(float* __restrict__ out, float v){
  out[blockIdx.x * 256 + threadIdx.x] = v;
}

extern "C" void kernel_launch(void* const* d_in, const int* in_sizes, int n_in,
                              void* d_out, int out_size, void* d_ws, size_t ws_size,
                              hipStream_t stream){
  const float* x    = (const float*)d_in[0];
  const float* sl   = (const float*)d_in[1];
  const float* mix  = (const float*)d_in[2];
  float* out = (float*)d_out;
  float* ws  = (float*)d_ws;

  int G = 64;
  size_t need = 0;
  for (;; G >>= 1){
    need = ((size_t)2*BN*NN + 2*(size_t)BN*KK*DD + BN*KK
            + (size_t)BN*G*KK*DD + (size_t)BN*G*KK) * sizeof(float);
    if (need <= ws_size || G == 8) break;
  }
  if (need > ws_size){
    k_fill<<<(BN*KK*DD)/256, 256, 0, stream>>>(out, -9.0f);   // diag: ws too small
    return;
  }

  size_t o = 0;
  float2* stats = (float2*)ws;            o += (size_t)2*BN*NN;
  float*  logqT = ws + o;                 o += (size_t)BN*KK*DD;
  float*  theta = ws + o;                 o += (size_t)BN*KK*DD;
  float*  logpi = ws + o;                 o += (size_t)BN*KK;
  float*  pnum  = ws + o;                 o += (size_t)BN*G*KK*DD;
  float*  ppi   = ws + o;

  k_rowstats  <<<BN*NN/4, 256, 0, stream>>>(x, stats);
  k_initparams<<<(BN*KK)/4, 256, 0, stream>>>(sl, mix, logqT, logpi);
  for (int it = 0; it < NITER; ++it){
    k_em2   <<<dim3(G, BN), 256, 0, stream>>>(x, stats, logqT, logpi, pnum, ppi, G);
    k_reduce<<<BN*KK, 64, 0, stream>>>(pnum, ppi, theta, logqT, logpi, G);
  }
  k_final<<<(BN*KK)/4, 256, 0, stream>>>(theta, out);
}

// Round 8
// 524.306 us; speedup vs baseline: 1.1704x; 1.1704x over previous
//
#include <hip/hip_runtime.h>
#include <cstdint>
#include <cstddef>

#define BN 8
#define NN 16384
#define DD 256
#define KK 16
#define NITER 5
#define EPSV 1e-8f
#define TILE 32
#define CHS 68              // chunk stride in words (68%32==4 -> disjoint bank quads)
#define RSTR 272            // row stride in words (4*CHS)

__device__ __forceinline__ float frcp(float x){ return __builtin_amdgcn_rcpf(x); }
__device__ __forceinline__ float rdlane(float v, int l){
  return __int_as_float(__builtin_amdgcn_readlane(__float_as_int(v), l));
}
__device__ __forceinline__ float wmax(float v){
  #pragma unroll
  for (int m = 32; m >= 1; m >>= 1) v = fmaxf(v, __shfl_xor(v, m, 64));
  return v;
}
__device__ __forceinline__ float wsum(float v){
  #pragma unroll
  for (int m = 32; m >= 1; m >>= 1) v += __shfl_xor(v, m, 64);
  return v;
}

// ---------------- row stats: per-row max and 1/sum(exp(x-max)) -------------
__global__ __launch_bounds__(256) void k_rowstats(const float* __restrict__ x,
                                                  float2* __restrict__ stats){
  int row  = blockIdx.x * 4 + (threadIdx.x >> 6);
  int lane = threadIdx.x & 63;
  const float4* xr = (const float4*)(x + (size_t)row * DD);
  float4 v = xr[lane];
  float m = wmax(fmaxf(fmaxf(v.x, v.y), fmaxf(v.z, v.w)));
  float s = wsum(__expf(v.x - m) + __expf(v.y - m) + __expf(v.z - m) + __expf(v.w - m));
  if (lane == 0) stats[row] = make_float2(m, frcp(s));
}

// ------------- init: logqT[b][d][k] = log_softmax(slot_logits), logpi0 -----
__global__ __launch_bounds__(256) void k_initparams(const float* __restrict__ slot_logits,
                                                    const float* __restrict__ mix,
                                                    float* __restrict__ logqT,
                                                    float* __restrict__ logpi){
  int w    = blockIdx.x * 4 + (threadIdx.x >> 6);   // w = b*K + k, 0..127
  int lane = threadIdx.x & 63;
  int b = w >> 4, k = w & 15;
  const float4* sl = (const float4*)(slot_logits + (size_t)k * DD);
  float4 t = sl[lane];
  float m = wmax(fmaxf(fmaxf(t.x, t.y), fmaxf(t.z, t.w)));
  float s = wsum(__expf(t.x - m) + __expf(t.y - m) + __expf(t.z - m) + __expf(t.w - m));
  float L = m + __logf(s);
  float* dq = logqT + (size_t)b * DD * KK;
  int d0 = lane * 4;
  dq[(d0+0)*KK + k] = t.x - L;
  dq[(d0+1)*KK + k] = t.y - L;
  dq[(d0+2)*KK + k] = t.z - L;
  dq[(d0+3)*KK + k] = t.w - L;
  if (lane == 0) logpi[w] = __logf(mix[k] + EPSV);
}

// ---------------- staging: wave-local 8 rows x 4 chunks --------------------
__device__ __forceinline__ void stage_tile(const float* __restrict__ xb, int n0,
                                           float* xl, int wave, int lane){
  #pragma unroll
  for (int ii = 0; ii < 32; ++ii){
    int r = (wave << 3) + (ii >> 2);    // 8 rows per wave
    int c = ii & 3;                     // 4 chunks of 64 floats
    const float* gp = xb + (size_t)(n0 + r) * DD + c * 64 + lane;
    float* lp = &xl[r * RSTR + c * CHS];   // wave-uniform base; HW adds lane*4
    __builtin_amdgcn_global_load_lds(
        (const __attribute__((address_space(1))) unsigned int*)gp,
        (__attribute__((address_space(3))) unsigned int*)lp, 4, 0, 0);
  }
}

// ------ fused EM iteration: wave-local tiles, lq in VGPRs, no barriers -----
__global__ __launch_bounds__(256, 3) void k_em3(const float* __restrict__ x,
                                                const float2* __restrict__ stats,
                                                const float* __restrict__ logqT,
                                                const float* __restrict__ logpi,
                                                float* __restrict__ pnum,
                                                float* __restrict__ ppi, int G){
  __shared__ float xl[TILE * RSTR];        // 34816 B
  __shared__ float spi2[16];

  const int b = blockIdx.y, g = blockIdx.x;
  const int tid  = threadIdx.x;
  const int wave = __builtin_amdgcn_readfirstlane(tid >> 6);
  const int lane = tid & 63;
  const int k    = lane & 15;              // slot owned by this lane
  const int ch   = lane >> 4;              // 64-dim chunk owned by this lane
  const int rows_pb = NN / G;
  const int tiles   = rows_pb / TILE;
  const int n00     = g * rows_pb;

  const float*  xb  = x + (size_t)b * NN * DD;
  const float2* stb = stats + (size_t)b * NN;

  // ---- preload lq column into 64 VGPRs: lqr[j] = logq[ch*64+j][k] ------
  float lqr[64];
  {
    const float* lqb = logqT + (size_t)b * DD * KK + (size_t)(ch * 64) * KK + k;
    #pragma unroll
    for (int j = 0; j < 64; ++j) lqr[j] = lqb[j * KK];
  }
  const float lpik = logpi[b * KK + k];

  float acc4[KK][4];
  #pragma unroll
  for (int kk2 = 0; kk2 < KK; ++kk2){
    acc4[kk2][0]=0.f; acc4[kk2][1]=0.f; acc4[kk2][2]=0.f; acc4[kk2][3]=0.f;
  }
  float piacc = 0.f;

  stage_tile(xb, n00, xl, wave, lane);

  for (int t = 0; t < tiles; ++t){
    const int n0 = n00 + t * TILE;
    asm volatile("s_waitcnt vmcnt(0)" ::: "memory");   // wave-local stage done

    // ---- exp-pass (wave-local rows): x -> e = exp(x - rowmax), in place ----
    {
      int rl  = (wave << 3) + (lane >> 3);   // wave's rows [8w, 8w+8)
      int seg = lane & 7;                    // 8 segments x 32 floats
      float mrow = stb[n0 + rl].x;
      float* pp = &xl[rl * RSTR + (seg >> 1) * CHS + (seg & 1) * 32];
      #pragma unroll
      for (int i = 0; i < 8; ++i){
        float4 v = *(float4*)&pp[4*i];
        v.x = __expf(v.x - mrow); v.y = __expf(v.y - mrow);
        v.z = __expf(v.z - mrow); v.w = __expf(v.w - mrow);
        *(float4*)&pp[4*i] = v;
      }
    }

    // ---- dot: per row, lane (k,ch) accumulates its 64-dim chunk ----------
    float tg[8];
    #pragma unroll
    for (int rr = 0; rr < 8; ++rr){
      const int r = (wave << 3) + rr;
      const float* pr = &xl[r * RSTR + ch * CHS];
      float a0 = 0.f, a1 = 0.f;
      #pragma unroll
      for (int i = 0; i < 16; ++i){
        float4 p4 = *(const float4*)&pr[4*i];
        a0 = fmaf(p4.x, lqr[4*i+0], a0);
        a1 = fmaf(p4.y, lqr[4*i+1], a1);
        a0 = fmaf(p4.z, lqr[4*i+2], a0);
        a1 = fmaf(p4.w, lqr[4*i+3], a1);
      }
      float ts = a0 + a1;
      ts += __shfl_xor(ts, 16, 64);
      ts += __shfl_xor(ts, 32, 64);          // full dot, all 4 chunk-copies
      tg[rr] = ts;
    }

    // ---- softmax over 16 slots (within 16-lane k-groups), 8 rows batched --
    #pragma unroll
    for (int rr = 0; rr < 8; ++rr){
      float2 st = stb[n0 + (wave << 3) + rr];
      float lg = fmaf(tg[rr], st.y, lpik);
      float mx = lg;
      #pragma unroll
      for (int m = 1; m <= 8; m <<= 1) mx = fmaxf(mx, __shfl_xor(mx, m, 64));
      float e = __expf(lg - mx);
      float s = e;
      #pragma unroll
      for (int m = 1; m <= 8; m <<= 1) s += __shfl_xor(s, m, 64);
      tg[rr] = e * frcp(s);                  // gamma
      piacc += tg[rr];
    }

    // ---- issue next-tile staging; accum hides its latency -----------------
    if (t + 1 < tiles) stage_tile(xb, n0 + TILE, xl, wave, lane);

    // ---- accum from global x (L2/L3-hot): lane owns d = 4*lane..4*lane+3 --
    #pragma unroll
    for (int rr = 0; rr < 8; ++rr){
      const int rg = n0 + (wave << 3) + rr;
      float4 x4 = ((const float4*)(xb + (size_t)rg * DD))[lane];
      #pragma unroll
      for (int k2 = 0; k2 < KK; ++k2){
        float gk = rdlane(tg[rr], k2);       // gamma[r][k2] lives in lane k2
        acc4[k2][0] = fmaf(gk, x4.x, acc4[k2][0]);
        acc4[k2][1] = fmaf(gk, x4.y, acc4[k2][1]);
        acc4[k2][2] = fmaf(gk, x4.z, acc4[k2][2]);
        acc4[k2][3] = fmaf(gk, x4.w, acc4[k2][3]);
      }
    }
  }

  // ---- epilogue: cross-wave reduce via LDS (xl reuse) ----------------------
  __syncthreads();
  float* sred = xl;                          // needs 16*260 = 4160 words
  if (wave == 0){
    #pragma unroll
    for (int k2 = 0; k2 < KK; ++k2)
      *(float4*)&sred[k2 * 260 + lane * 4] =
          make_float4(acc4[k2][0], acc4[k2][1], acc4[k2][2], acc4[k2][3]);
    if (lane < KK) spi2[lane] = piacc;
  }
  __syncthreads();
  for (int w = 1; w < 4; ++w){
    if (wave == w){
      #pragma unroll
      for (int k2 = 0; k2 < KK; ++k2){
        float4 t4 = *(float4*)&sred[k2 * 260 + lane * 4];
        t4.x += acc4[k2][0]; t4.y += acc4[k2][1];
        t4.z += acc4[k2][2]; t4.w += acc4[k2][3];
        *(float4*)&sred[k2 * 260 + lane * 4] = t4;
      }
      if (lane < KK) spi2[lane] += piacc;
    }
    __syncthreads();
  }
  float* dst = pnum + (size_t)(b * G + g) * KK * DD;
  for (int i = tid; i < KK * DD; i += 256){
    int k2 = i >> 8, d = i & 255;
    dst[i] = sred[k2 * 260 + d];
  }
  if (tid < KK) ppi[(size_t)(b * G + g) * KK + tid] = spi2[tid];
}

// ---------------- reduce partials -> theta, logqT, log_pi ------------------
__global__ __launch_bounds__(64) void k_reduce(const float* __restrict__ pnum,
                                               const float* __restrict__ ppi,
                                               float* __restrict__ theta,
                                               float* __restrict__ logqT,
                                               float* __restrict__ logpi, int G){
  int w = blockIdx.x;              // b*K + k
  int lane = threadIdx.x;
  int b = w >> 4, k = w & 15;
  float4 sum = make_float4(0.f, 0.f, 0.f, 0.f);
  const float4* base = (const float4*)pnum + ((size_t)b * G * KK + k) * (DD/4) + lane;
  #pragma unroll 4
  for (int g = 0; g < G; ++g){
    float4 t = base[(size_t)g * KK * (DD/4)];
    sum.x += t.x; sum.y += t.y; sum.z += t.z; sum.w += t.w;
  }
  float ps = 0.f;
  for (int g = lane; g < G; g += 64) ps += ppi[((size_t)b * G + g) * KK + k];
  ps = wsum(ps);
  float inv = frcp(ps + EPSV);
  float4 th = make_float4(sum.x * inv, sum.y * inv, sum.z * inv, sum.w * inv);
  ((float4*)(theta + (size_t)w * DD))[lane] = th;
  float m = wmax(fmaxf(fmaxf(th.x, th.y), fmaxf(th.z, th.w)));
  float s = wsum(__expf(th.x - m) + __expf(th.y - m) + __expf(th.z - m) + __expf(th.w - m));
  float L = m + __logf(s);
  float* dq = logqT + (size_t)b * DD * KK;
  int d0 = lane * 4;
  dq[(d0+0)*KK + k] = th.x - L;
  dq[(d0+1)*KK + k] = th.y - L;
  dq[(d0+2)*KK + k] = th.z - L;
  dq[(d0+3)*KK + k] = th.w - L;
  if (lane == 0) logpi[w] = __logf(ps * (1.0f / NN) + EPSV);
}

// ---------------- threefry2x32-20 core (general key) -----------------------
__device__ __forceinline__ uint32_t rotl32(uint32_t x, int r){ return (x << r) | (x >> (32 - r)); }
__device__ __forceinline__ void tf2x32(uint32_t k0, uint32_t k1, uint32_t c0, uint32_t c1,
                                       uint32_t& o0, uint32_t& o1){
  uint32_t ks0 = k0, ks1 = k1, ks2 = 0x1BD11BDAu ^ k0 ^ k1;
  uint32_t x0 = c0 + ks0, x1 = c1 + ks1;
  #define RND(r) { x0 += x1; x1 = rotl32(x1, r); x1 ^= x0; }
  RND(13) RND(15) RND(26) RND(6)   x0 += ks1; x1 += ks2 + 1u;
  RND(17) RND(29) RND(16) RND(24)  x0 += ks2; x1 += ks0 + 2u;
  RND(13) RND(15) RND(26) RND(6)   x0 += ks0; x1 += ks1 + 3u;
  RND(17) RND(29) RND(16) RND(24)  x0 += ks1; x1 += ks2 + 4u;
  RND(13) RND(15) RND(26) RND(6)   x0 += ks2; x1 += ks0 + 5u;
  #undef RND
  o0 = x0; o1 = x1;
}

// ---------------- final: gumbel (partitionable XOR-fold, VERIFIED) ---------
__global__ __launch_bounds__(256) void k_final(const float* __restrict__ theta,
                                               float* __restrict__ out){
  int w    = blockIdx.x * 4 + (threadIdx.x >> 6);   // b*K + k
  int lane = threadIdx.x & 63;
  float4 th = ((const float4*)(theta + (size_t)w * DD))[lane];
  int i0 = w * DD + lane * 4;
  float gv[4];
  #pragma unroll
  for (int j = 0; j < 4; ++j){
    uint32_t i = (uint32_t)(i0 + j);
    uint32_t o0, o1;
    tf2x32(0u, 1u, 0u, i, o0, o1);      // ctr = (hi=0, lo=i)
    uint32_t bits = o0 ^ o1;            // partitionable <=32-bit: bits1 ^ bits2
    float f = __uint_as_float((bits >> 9) | 0x3f800000u) - 1.0f;
    const float TINY = 1.17549435e-38f;
    float u = fmaxf(f + TINY, TINY);
    gv[j] = -logf(-logf(u));
  }
  float4 y = make_float4(th.x + gv[0], th.y + gv[1], th.z + gv[2], th.w + gv[3]);
  float m = wmax(fmaxf(fmaxf(y.x, y.y), fmaxf(y.z, y.w)));
  float4 e = make_float4(__expf(y.x - m), __expf(y.y - m), __expf(y.z - m), __expf(y.w - m));
  float s = wsum(e.x + e.y + e.z + e.w);
  float inv = 1.0f / s;
  ((float4*)(out + (size_t)w * DD))[lane] =
      make_float4(e.x * inv, e.y * inv, e.z * inv, e.w * inv);
}

__global__ __launch_bounds__(256) void k_fill(float* __restrict__ out, float v){
  out[blockIdx.x * 256 + threadIdx.x] = v;
}

extern "C" void kernel_launch(void* const* d_in, const int* in_sizes, int n_in,
                              void* d_out, int out_size, void* d_ws, size_t ws_size,
                              hipStream_t stream){
  const float* x    = (const float*)d_in[0];
  const float* sl   = (const float*)d_in[1];
  const float* mix  = (const float*)d_in[2];
  float* out = (float*)d_out;
  float* ws  = (float*)d_ws;

  int G = 128;
  size_t need = 0;
  for (;; G >>= 1){
    need = ((size_t)2*BN*NN + 2*(size_t)BN*KK*DD + BN*KK
            + (size_t)BN*G*KK*DD + (size_t)BN*G*KK) * sizeof(float);
    if (need <= ws_size || G == 8) break;
  }
  if (need > ws_size){
    k_fill<<<(BN*KK*DD)/256, 256, 0, stream>>>(out, -9.0f);   // diag: ws too small
    return;
  }

  size_t o = 0;
  float2* stats = (float2*)ws;            o += (size_t)2*BN*NN;
  float*  logqT = ws + o;                 o += (size_t)BN*KK*DD;
  float*  theta = ws + o;                 o += (size_t)BN*KK*DD;
  float*  logpi = ws + o;                 o += (size_t)BN*KK;
  float*  pnum  = ws + o;                 o += (size_t)BN*G*KK*DD;
  float*  ppi   = ws + o;

  k_rowstats  <<<BN*NN/4, 256, 0, stream>>>(x, stats);
  k_initparams<<<(BN*KK)/4, 256, 0, stream>>>(sl, mix, logqT, logpi);
  for (int it = 0; it < NITER; ++it){
    k_em3   <<<dim3(G, BN), 256, 0, stream>>>(x, stats, logqT, logpi, pnum, ppi, G);
    k_reduce<<<BN*KK, 64, 0, stream>>>(pnum, ppi, theta, logqT, logpi, G);
  }
  k_final<<<(BN*KK)/4, 256, 0, stream>>>(theta, out);
}

// Round 9
// 441.555 us; speedup vs baseline: 1.3897x; 1.1874x over previous
//
#include <hip/hip_runtime.h>
#include <cstdint>
#include <cstddef>

#define BN 8
#define NN 16384
#define DD 256
#define KK 16
#define NITER 5
#define EPSV 1e-8f
#define TILE 16

__device__ __forceinline__ float frcp(float x){ return __builtin_amdgcn_rcpf(x); }
__device__ __forceinline__ float rdlane(float v, int l){
  return __int_as_float(__builtin_amdgcn_readlane(__float_as_int(v), l));
}
__device__ __forceinline__ float wmax(float v){
  #pragma unroll
  for (int m = 32; m >= 1; m >>= 1) v = fmaxf(v, __shfl_xor(v, m, 64));
  return v;
}
__device__ __forceinline__ float wsum(float v){
  #pragma unroll
  for (int m = 32; m >= 1; m >>= 1) v += __shfl_xor(v, m, 64);
  return v;
}

// ---------------- row stats: per-row max and 1/sum(exp(x-max)) -------------
__global__ __launch_bounds__(256) void k_rowstats(const float* __restrict__ x,
                                                  float2* __restrict__ stats){
  int row  = blockIdx.x * 4 + (threadIdx.x >> 6);
  int lane = threadIdx.x & 63;
  const float4* xr = (const float4*)(x + (size_t)row * DD);
  float4 v = xr[lane];
  float m = wmax(fmaxf(fmaxf(v.x, v.y), fmaxf(v.z, v.w)));
  float s = wsum(__expf(v.x - m) + __expf(v.y - m) + __expf(v.z - m) + __expf(v.w - m));
  if (lane == 0) stats[row] = make_float2(m, frcp(s));
}

// ---------------- init: log_q0 = log_softmax(slot_logits), logpi0 ----------
__global__ __launch_bounds__(256) void k_initparams(const float* __restrict__ slot_logits,
                                                    const float* __restrict__ mix,
                                                    float* __restrict__ logq,
                                                    float* __restrict__ logpi){
  int w    = blockIdx.x * 4 + (threadIdx.x >> 6);   // w = b*K + k, 0..127
  int lane = threadIdx.x & 63;
  int k = w & 15;
  const float4* sl = (const float4*)(slot_logits + (size_t)k * DD);
  float4 t = sl[lane];
  float m = wmax(fmaxf(fmaxf(t.x, t.y), fmaxf(t.z, t.w)));
  float s = wsum(__expf(t.x - m) + __expf(t.y - m) + __expf(t.z - m) + __expf(t.w - m));
  float L = m + __logf(s);
  ((float4*)(logq + (size_t)w * DD))[lane] = make_float4(t.x - L, t.y - L, t.z - L, t.w - L);
  if (lane == 0) logpi[w] = __logf(mix[k] + EPSV);
}

// ---------------- staging: 4 rows per wave, width-16 gload_lds -------------
__device__ __forceinline__ void stage4(const float* __restrict__ xb, int n0,
                                       int wave, int lane, float* dstbase){
  #pragma unroll
  for (int r = 0; r < 4; ++r){
    int row = wave * 4 + r;
    const float* gp = xb + (size_t)(n0 + row) * DD + lane * 4;   // per-lane 16B
    float* lp = dstbase + row * DD;                              // wave-uniform
    __builtin_amdgcn_global_load_lds(
        (const __attribute__((address_space(1))) unsigned int*)gp,
        (__attribute__((address_space(3))) unsigned int*)lp, 16, 0, 0);
  }
}

// ------ fused EM iteration: barrier-free waves, non-redundant LDS reads ----
__global__ __launch_bounds__(256, 2) void k_em4(const float* __restrict__ x,
                                                const float2* __restrict__ stats,
                                                const float* __restrict__ logq,
                                                const float* __restrict__ logpi,
                                                float* __restrict__ pnum,
                                                float* __restrict__ ppi, int G){
  __shared__ float xl[2][TILE * DD];   // 32 KB double-buffered raw x
  __shared__ float pl[TILE * DD];      // 16 KB normalized p
  __shared__ float spi2[16];

  const int b = blockIdx.y, g = blockIdx.x;
  const int tid  = threadIdx.x;
  const int wave = __builtin_amdgcn_readfirstlane(tid >> 6);
  const int lane = tid & 63;
  const int rows_pb = NN / G;
  const int tiles   = rows_pb / TILE;
  const int n00     = g * rows_pb;

  const float*  xb  = x + (size_t)b * NN * DD;
  const float2* stb = stats + (size_t)b * NN;

  // per-lane fragment of log_q: q[k] = logq[b][k][4*lane .. 4*lane+3]
  const float4* lq4 = (const float4*)(logq + (size_t)b * KK * DD);
  float4 q[KK];
  #pragma unroll
  for (int k = 0; k < KK; ++k) q[k] = lq4[k * (DD/4) + lane];
  const float lpik = logpi[b * KK + (lane & 15)];

  float acc4[KK][4];
  #pragma unroll
  for (int k = 0; k < KK; ++k){ acc4[k][0]=0.f; acc4[k][1]=0.f; acc4[k][2]=0.f; acc4[k][3]=0.f; }
  float piacc = 0.f;

  stage4(xb, n00, wave, lane, &xl[0][0]);

  for (int t = 0; t < tiles; ++t){
    const int n0  = n00 + t * TILE;
    const int cur = t & 1;
    float* xcur = &xl[cur][0];
    asm volatile("s_waitcnt vmcnt(0)" ::: "memory");
    __builtin_amdgcn_sched_barrier(0);
    if (t + 1 < tiles) stage4(xb, n0 + TILE, wave, lane, &xl[cur ^ 1][0]);

    // ---- exp phase: wave's 4 rows, strided b32 (2-way, free); fold invs ---
    #pragma unroll
    for (int r = 0; r < 4; ++r){
      const int row = wave * 4 + r;
      float2 st = stb[n0 + row];
      #pragma unroll
      for (int c = 0; c < 4; ++c){
        float v = xcur[row * DD + c * 64 + lane];
        pl[row * DD + c * 64 + lane] = __expf(v - st.x) * st.y;
      }
    }

    // ---- dot + softmax per row: 1 contiguous b128 + 64 FMA + butterfly ----
    float tg[4];
    #pragma unroll
    for (int r = 0; r < 4; ++r){
      const int row = wave * 4 + r;
      float4 p4 = *(const float4*)&pl[row * DD + lane * 4];
      float v[KK];
      #pragma unroll
      for (int k = 0; k < KK; ++k)
        v[k] = fmaf(p4.w, q[k].w, fmaf(p4.z, q[k].z, fmaf(p4.y, q[k].y, p4.x * q[k].x)));
      // segmented tree reduce within 16-lane groups (verified r5)
      {
        bool up = (lane & 8) != 0;
        #pragma unroll
        for (int j = 0; j < 8; ++j){
          float lo = v[j], hi = v[j+8];
          float recv = __shfl_xor(up ? lo : hi, 8, 64);
          v[j] = (up ? hi : lo) + recv;
        }
      }
      {
        bool up = (lane & 4) != 0;
        #pragma unroll
        for (int j = 0; j < 4; ++j){
          float lo = v[j], hi = v[j+4];
          float recv = __shfl_xor(up ? lo : hi, 4, 64);
          v[j] = (up ? hi : lo) + recv;
        }
      }
      {
        bool up = (lane & 2) != 0;
        #pragma unroll
        for (int j = 0; j < 2; ++j){
          float lo = v[j], hi = v[j+2];
          float recv = __shfl_xor(up ? lo : hi, 2, 64);
          v[j] = (up ? hi : lo) + recv;
        }
      }
      {
        bool up = (lane & 1) != 0;
        float lo = v[0], hi = v[1];
        float recv = __shfl_xor(up ? lo : hi, 1, 64);
        v[0] = (up ? hi : lo) + recv;
      }
      float T = v[0];
      T += __shfl_xor(T, 16, 64);
      T += __shfl_xor(T, 32, 64);              // full dot (p pre-normalized)
      float lg = T + lpik;
      float mx = lg;
      #pragma unroll
      for (int m = 1; m <= 8; m <<= 1) mx = fmaxf(mx, __shfl_xor(mx, m, 64));
      float e = __expf(lg - mx);
      float s = e;
      #pragma unroll
      for (int m = 1; m <= 8; m <<= 1) s += __shfl_xor(s, m, 64);
      tg[r] = e * frcp(s);                     // gamma, slot=lane&15
      piacc += tg[r];
    }

    // ---- accum: x from LDS strided b32; lane owns d = 64c + lane ----------
    #pragma unroll
    for (int r = 0; r < 4; ++r){
      const int row = wave * 4 + r;
      float xv0 = xcur[row * DD +   0 + lane];
      float xv1 = xcur[row * DD +  64 + lane];
      float xv2 = xcur[row * DD + 128 + lane];
      float xv3 = xcur[row * DD + 192 + lane];
      #pragma unroll
      for (int k2 = 0; k2 < KK; ++k2){
        float gk = rdlane(tg[r], k2);
        acc4[k2][0] = fmaf(gk, xv0, acc4[k2][0]);
        acc4[k2][1] = fmaf(gk, xv1, acc4[k2][1]);
        acc4[k2][2] = fmaf(gk, xv2, acc4[k2][2]);
        acc4[k2][3] = fmaf(gk, xv3, acc4[k2][3]);
      }
    }
  }

  // ---- epilogue: cross-wave reduce via LDS; sred layout == pnum layout ----
  __syncthreads();
  float* sred = &xl[0][0];                     // 4096 words
  if (wave == 0){
    #pragma unroll
    for (int k2 = 0; k2 < KK; ++k2)
      #pragma unroll
      for (int c = 0; c < 4; ++c)
        sred[k2 * DD + c * 64 + lane] = acc4[k2][c];
    if (lane < KK) spi2[lane] = piacc;
  }
  __syncthreads();
  for (int w = 1; w < 4; ++w){
    if (wave == w){
      #pragma unroll
      for (int k2 = 0; k2 < KK; ++k2)
        #pragma unroll
        for (int c = 0; c < 4; ++c)
          sred[k2 * DD + c * 64 + lane] += acc4[k2][c];
      if (lane < KK) spi2[lane] += piacc;
    }
    __syncthreads();
  }
  float4* dst4 = (float4*)(pnum + (size_t)(b * G + g) * KK * DD);
  const float4* s4 = (const float4*)sred;
  #pragma unroll
  for (int j = 0; j < 4; ++j) dst4[tid + j * 256] = s4[tid + j * 256];
  if (tid < KK) ppi[(size_t)(b * G + g) * KK + tid] = spi2[tid];
}

// ---------------- reduce partials -> theta, log_q, log_pi ------------------
__global__ __launch_bounds__(64) void k_reduce(const float* __restrict__ pnum,
                                               const float* __restrict__ ppi,
                                               float* __restrict__ theta,
                                               float* __restrict__ logq,
                                               float* __restrict__ logpi, int G){
  int w = blockIdx.x;              // b*K + k
  int lane = threadIdx.x;
  int b = w >> 4, k = w & 15;
  float4 sum = make_float4(0.f, 0.f, 0.f, 0.f);
  const float4* base = (const float4*)pnum + ((size_t)b * G * KK + k) * (DD/4) + lane;
  #pragma unroll 4
  for (int g = 0; g < G; ++g){
    float4 t = base[(size_t)g * KK * (DD/4)];
    sum.x += t.x; sum.y += t.y; sum.z += t.z; sum.w += t.w;
  }
  float ps = 0.f;
  for (int g = lane; g < G; g += 64) ps += ppi[((size_t)b * G + g) * KK + k];
  ps = wsum(ps);
  float inv = frcp(ps + EPSV);
  float4 th = make_float4(sum.x * inv, sum.y * inv, sum.z * inv, sum.w * inv);
  ((float4*)(theta + (size_t)w * DD))[lane] = th;
  float m = wmax(fmaxf(fmaxf(th.x, th.y), fmaxf(th.z, th.w)));
  float s = wsum(__expf(th.x - m) + __expf(th.y - m) + __expf(th.z - m) + __expf(th.w - m));
  float L = m + __logf(s);
  ((float4*)(logq + (size_t)w * DD))[lane] = make_float4(th.x - L, th.y - L, th.z - L, th.w - L);
  if (lane == 0) logpi[w] = __logf(ps * (1.0f / NN) + EPSV);
}

// ---------------- threefry2x32-20 core (general key) -----------------------
__device__ __forceinline__ uint32_t rotl32(uint32_t x, int r){ return (x << r) | (x >> (32 - r)); }
__device__ __forceinline__ void tf2x32(uint32_t k0, uint32_t k1, uint32_t c0, uint32_t c1,
                                       uint32_t& o0, uint32_t& o1){
  uint32_t ks0 = k0, ks1 = k1, ks2 = 0x1BD11BDAu ^ k0 ^ k1;
  uint32_t x0 = c0 + ks0, x1 = c1 + ks1;
  #define RND(r) { x0 += x1; x1 = rotl32(x1, r); x1 ^= x0; }
  RND(13) RND(15) RND(26) RND(6)   x0 += ks1; x1 += ks2 + 1u;
  RND(17) RND(29) RND(16) RND(24)  x0 += ks2; x1 += ks0 + 2u;
  RND(13) RND(15) RND(26) RND(6)   x0 += ks0; x1 += ks1 + 3u;
  RND(17) RND(29) RND(16) RND(24)  x0 += ks1; x1 += ks2 + 4u;
  RND(13) RND(15) RND(26) RND(6)   x0 += ks2; x1 += ks0 + 5u;
  #undef RND
  o0 = x0; o1 = x1;
}

// ---------------- final: gumbel (partitionable XOR-fold, VERIFIED) ---------
__global__ __launch_bounds__(256) void k_final(const float* __restrict__ theta,
                                               float* __restrict__ out){
  int w    = blockIdx.x * 4 + (threadIdx.x >> 6);   // b*K + k
  int lane = threadIdx.x & 63;
  float4 th = ((const float4*)(theta + (size_t)w * DD))[lane];
  int i0 = w * DD + lane * 4;
  float gv[4];
  #pragma unroll
  for (int j = 0; j < 4; ++j){
    uint32_t i = (uint32_t)(i0 + j);
    uint32_t o0, o1;
    tf2x32(0u, 1u, 0u, i, o0, o1);      // ctr = (hi=0, lo=i)
    uint32_t bits = o0 ^ o1;            // partitionable <=32-bit: bits1 ^ bits2
    float f = __uint_as_float((bits >> 9) | 0x3f800000u) - 1.0f;
    const float TINY = 1.17549435e-38f;
    float u = fmaxf(f + TINY, TINY);
    gv[j] = -logf(-logf(u));
  }
  float4 y = make_float4(th.x + gv[0], th.y + gv[1], th.z + gv[2], th.w + gv[3]);
  float m = wmax(fmaxf(fmaxf(y.x, y.y), fmaxf(y.z, y.w)));
  float4 e = make_float4(__expf(y.x - m), __expf(y.y - m), __expf(y.z - m), __expf(y.w - m));
  float s = wsum(e.x + e.y + e.z + e.w);
  float inv = 1.0f / s;
  ((float4*)(out + (size_t)w * DD))[lane] =
      make_float4(e.x * inv, e.y * inv, e.z * inv, e.w * inv);
}

__global__ __launch_bounds__(256) void k_fill(float* __restrict__ out, float v){
  out[blockIdx.x * 256 + threadIdx.x] = v;
}

extern "C" void kernel_launch(void* const* d_in, const int* in_sizes, int n_in,
                              void* d_out, int out_size, void* d_ws, size_t ws_size,
                              hipStream_t stream){
  const float* x    = (const float*)d_in[0];
  const float* sl   = (const float*)d_in[1];
  const float* mix  = (const float*)d_in[2];
  float* out = (float*)d_out;
  float* ws  = (float*)d_ws;

  int G = 64;
  size_t need = 0;
  for (;; G >>= 1){
    need = ((size_t)2*BN*NN + 2*(size_t)BN*KK*DD + BN*KK
            + (size_t)BN*G*KK*DD + (size_t)BN*G*KK) * sizeof(float);
    if (need <= ws_size || G == 8) break;
  }
  if (need > ws_size){
    k_fill<<<(BN*KK*DD)/256, 256, 0, stream>>>(out, -9.0f);   // diag: ws too small
    return;
  }

  size_t o = 0;
  float2* stats = (float2*)ws;            o += (size_t)2*BN*NN;
  float*  logq  = ws + o;                 o += (size_t)BN*KK*DD;
  float*  theta = ws + o;                 o += (size_t)BN*KK*DD;
  float*  logpi = ws + o;                 o += (size_t)BN*KK;
  float*  pnum  = ws + o;                 o += (size_t)BN*G*KK*DD;
  float*  ppi   = ws + o;

  k_rowstats  <<<BN*NN/4, 256, 0, stream>>>(x, stats);
  k_initparams<<<(BN*KK)/4, 256, 0, stream>>>(sl, mix, logq, logpi);
  for (int it = 0; it < NITER; ++it){
    k_em4   <<<dim3(G, BN), 256, 0, stream>>>(x, stats, logq, logpi, pnum, ppi, G);
    k_reduce<<<BN*KK, 64, 0, stream>>>(pnum, ppi, theta, logq, logpi, G);
  }
  k_final<<<(BN*KK)/4, 256, 0, stream>>>(theta, out);
}

// Round 10
// 211.052 us; speedup vs baseline: 2.9075x; 2.0922x over previous
//
#include <hip/hip_runtime.h>
#include <cstdint>
#include <cstddef>

#define BN 8
#define NN 16384
#define DD 256
#define KK 16
#define NITER 5
#define EPSV 1e-8f
#define LOG256 5.545177444479562f
#define PSTR 258

typedef short bf16x8 __attribute__((ext_vector_type(8)));
typedef float f32x4 __attribute__((ext_vector_type(4)));

__device__ __forceinline__ float frcp(float x){ return __builtin_amdgcn_rcpf(x); }
__device__ __forceinline__ float rdlane(float v, int l){
  return __int_as_float(__builtin_amdgcn_readlane(__float_as_int(v), l));
}
__device__ __forceinline__ float wmax(float v){
  #pragma unroll
  for (int m = 32; m >= 1; m >>= 1) v = fmaxf(v, __shfl_xor(v, m, 64));
  return v;
}
__device__ __forceinline__ float wsum(float v){
  #pragma unroll
  for (int m = 32; m >= 1; m >>= 1) v += __shfl_xor(v, m, 64);
  return v;
}
__device__ __forceinline__ uint32_t f2bf(float f){   // RNE f32->bf16
  uint32_t u = __float_as_uint(f);
  return (u + 0x7fffu + ((u >> 16) & 1u)) >> 16;
}
__device__ __forceinline__ uint32_t pk2(float a, float b){
  return f2bf(a) | (f2bf(b) << 16);
}

// ======================= NEW MFMA PATH =====================================

// ---- prologue: row stats + emit pbf (A-frags) and xbf (B-frags) -----------
// pbf: [b][chunk=2S+c][s=8][lane][8bf16]; element j: p_norm[n][32s+8(l>>4)+j],
//      n = 8*(rho>>2) + 4c + (rho&3), rho = lane&15 (row-interleaved chunks)
// xbf: [b][S][dt=16][lane][8bf16]; element j: x[8*(l>>4)+j][16dt + (lane&15)]
__global__ __launch_bounds__(256) void k_prep(const float* __restrict__ x,
                                              uint4* __restrict__ pbf,
                                              uint4* __restrict__ xbf){
  __shared__ float xs[32 * PSTR];
  __shared__ float sm[32], si[32];
  const int b = blockIdx.y, S = blockIdx.x;          // S: 0..511
  const int tid = threadIdx.x;
  const int wave = tid >> 6, lane = tid & 63;
  const float* xb = x + ((size_t)b * NN + (size_t)S * 32) * DD;

  #pragma unroll
  for (int r = 0; r < 8; ++r){
    int row = wave * 8 + r;
    const float* gp = xb + (size_t)row * DD + lane * 4;
    float* lp = &xs[row * PSTR];
    __builtin_amdgcn_global_load_lds(
        (const __attribute__((address_space(1))) unsigned int*)gp,
        (__attribute__((address_space(3))) unsigned int*)lp, 16, 0, 0);
  }
  asm volatile("s_waitcnt vmcnt(0)" ::: "memory");
  #pragma unroll
  for (int r = 0; r < 8; ++r){
    int row = wave * 8 + r;
    float4 v = *(const float4*)&xs[row * PSTR + lane * 4];
    float m = wmax(fmaxf(fmaxf(v.x, v.y), fmaxf(v.z, v.w)));
    float s = wsum(__expf(v.x-m) + __expf(v.y-m) + __expf(v.z-m) + __expf(v.w-m));
    if (lane == 0){ sm[row] = m; si[row] = frcp(s); }
  }
  __syncthreads();

  // pbf: wave handles 4 (c,s) pairs
  #pragma unroll
  for (int i = 0; i < 4; ++i){
    int p = wave * 4 + i; int c = p >> 3, s = p & 7;
    int rho = lane & 15;
    int n = 8 * (rho >> 2) + 4 * c + (rho & 3);
    int d = 32 * s + 8 * (lane >> 4);
    float m = sm[n], inv = si[n];
    float4 v0 = *(const float4*)&xs[n * PSTR + d];
    float4 v1 = *(const float4*)&xs[n * PSTR + d + 4];
    uint4 o;
    o.x = pk2(__expf(v0.x-m)*inv, __expf(v0.y-m)*inv);
    o.y = pk2(__expf(v0.z-m)*inv, __expf(v0.w-m)*inv);
    o.z = pk2(__expf(v1.x-m)*inv, __expf(v1.y-m)*inv);
    o.w = pk2(__expf(v1.z-m)*inv, __expf(v1.w-m)*inv);
    pbf[(((size_t)b * 1024 + (size_t)S * 2 + c) * 8 + s) * 64 + lane] = o;
  }
  // xbf: wave handles 4 dtiles
  #pragma unroll
  for (int i = 0; i < 4; ++i){
    int dt = wave * 4 + i;
    int col = dt * 16 + (lane & 15);
    int g2 = lane >> 4;
    float v[8];
    #pragma unroll
    for (int j = 0; j < 8; ++j) v[j] = xs[(8 * g2 + j) * PSTR + col];
    uint4 o;
    o.x = pk2(v[0], v[1]); o.y = pk2(v[2], v[3]);
    o.z = pk2(v[4], v[5]); o.w = pk2(v[6], v[7]);
    xbf[(((size_t)b * 512 + S) * 16 + dt) * 64 + lane] = o;
  }
}

// ---- init: logq B-frags (resid = logsoftmax + log256, bf16) + logpi -------
__global__ __launch_bounds__(256) void k_init5(const float* __restrict__ slot_logits,
                                               const float* __restrict__ mix,
                                               uint16_t* __restrict__ lqf,
                                               float* __restrict__ logpi){
  int w    = blockIdx.x * 4 + (threadIdx.x >> 6);   // b*K + k
  int lane = threadIdx.x & 63;
  int b = w >> 4, k = w & 15;
  const float4* sl = (const float4*)(slot_logits + (size_t)k * DD);
  float4 t = sl[lane];
  float m = wmax(fmaxf(fmaxf(t.x, t.y), fmaxf(t.z, t.w)));
  float s = wsum(__expf(t.x-m) + __expf(t.y-m) + __expf(t.z-m) + __expf(t.w-m));
  float L = m + __logf(s);
  int d0 = lane * 4;
  int ss = d0 >> 5;
  int l2 = (((d0 & 31) >> 3) << 4) + k;
  int jb = d0 & 7;
  uint2 o;
  o.x = pk2(t.x - L + LOG256, t.y - L + LOG256);
  o.y = pk2(t.z - L + LOG256, t.w - L + LOG256);
  *(uint2*)(lqf + ((((size_t)b * 8 + ss) * 64 + l2) * 8 + jb)) = o;
  if (lane == 0) logpi[w] = __logf(mix[k] + EPSV);
}

// ---- fused EM iteration via MFMA ------------------------------------------
__global__ __launch_bounds__(256, 2) void k_em5(const uint4* __restrict__ pbf,
                                                const uint4* __restrict__ xbf,
                                                const uint4* __restrict__ lqf,
                                                const float* __restrict__ logpi,
                                                float* __restrict__ pnum,
                                                float* __restrict__ ppi){
  __shared__ float sred[KK * DD];
  __shared__ float spi2[16];
  const int b = blockIdx.y, g = blockIdx.x;          // g: 0..63
  const int tid = threadIdx.x;
  const int wave = tid >> 6, lane = tid & 63;

  bf16x8 lqv[8];
  {
    const uint4* p = lqf + (size_t)b * 8 * 64 + lane;
    #pragma unroll
    for (int s = 0; s < 8; ++s){ uint4 t = p[s * 64]; lqv[s] = *(bf16x8*)&t; }
  }
  const float lpik = logpi[b * KK + (lane & 15)];

  f32x4 acc[16];
  #pragma unroll
  for (int dt = 0; dt < 16; ++dt) acc[dt] = (f32x4){0.f, 0.f, 0.f, 0.f};
  float piacc = 0.f;

  const int S0 = (g * 4 + wave) * 2;
  #pragma unroll
  for (int ssi = 0; ssi < 2; ++ssi){
    const int S = S0 + ssi;
    const uint4* pb = pbf + (((size_t)b * 1024 + (size_t)S * 2) * 8) * 64 + lane;
    const uint4* xr = xbf + (((size_t)b * 512 + S) * 16) * 64 + lane;

    uint4 pa[16];
    #pragma unroll
    for (int i = 0; i < 16; ++i) pa[i] = pb[(size_t)i * 64];   // [c*8+s]

    float ga[8];
    #pragma unroll
    for (int c = 0; c < 2; ++c){
      f32x4 lc = (f32x4){0.f, 0.f, 0.f, 0.f};
      #pragma unroll
      for (int s = 0; s < 8; ++s){
        bf16x8 a = *(bf16x8*)&pa[c * 8 + s];
        lc = __builtin_amdgcn_mfma_f32_16x16x32_bf16(a, lqv[s], lc, 0, 0, 0);
      }
      #pragma unroll
      for (int r2 = 0; r2 < 4; ++r2){
        float lg = lc[r2] + lpik;
        float mx = lg;
        #pragma unroll
        for (int m = 1; m <= 8; m <<= 1) mx = fmaxf(mx, __shfl_xor(mx, m, 64));
        float e = __expf(lg - mx);
        float s2 = e;
        #pragma unroll
        for (int m = 1; m <= 8; m <<= 1) s2 += __shfl_xor(s2, m, 64);
        float gv = e * frcp(s2);
        ga[c * 4 + r2] = gv;
        piacc += gv;
      }
    }
    uint4 gp;
    gp.x = pk2(ga[0], ga[1]); gp.y = pk2(ga[2], ga[3]);
    gp.z = pk2(ga[4], ga[5]); gp.w = pk2(ga[6], ga[7]);
    bf16x8 gA = *(bf16x8*)&gp;
    #pragma unroll
    for (int dt = 0; dt < 16; ++dt){
      uint4 xv = xr[(size_t)dt * 64];
      bf16x8 xB = *(bf16x8*)&xv;
      acc[dt] = __builtin_amdgcn_mfma_f32_16x16x32_bf16(gA, xB, acc[dt], 0, 0, 0);
    }
  }

  // epilogue: cross-wave reduce
  float pk = piacc;
  pk += __shfl_xor(pk, 16, 64);
  pk += __shfl_xor(pk, 32, 64);
  __syncthreads();
  if (wave == 0){
    #pragma unroll
    for (int dt = 0; dt < 16; ++dt)
      #pragma unroll
      for (int r2 = 0; r2 < 4; ++r2)
        sred[(4 * (lane >> 4) + r2) * DD + dt * 16 + (lane & 15)] = acc[dt][r2];
    if (lane < 16) spi2[lane] = pk;
  }
  __syncthreads();
  for (int w = 1; w < 4; ++w){
    if (wave == w){
      #pragma unroll
      for (int dt = 0; dt < 16; ++dt)
        #pragma unroll
        for (int r2 = 0; r2 < 4; ++r2)
          sred[(4 * (lane >> 4) + r2) * DD + dt * 16 + (lane & 15)] += acc[dt][r2];
      if (lane < 16) spi2[lane] += pk;
    }
    __syncthreads();
  }
  float4* dst4 = (float4*)(pnum + (size_t)(b * 64 + g) * KK * DD);
  const float4* s4 = (const float4*)sred;
  #pragma unroll
  for (int j = 0; j < 4; ++j) dst4[tid + j * 256] = s4[tid + j * 256];
  if (tid < 16) ppi[(size_t)(b * 64 + g) * KK + tid] = spi2[tid];
}

// ---- reduce partials -> theta, lqf frags, log_pi (G=64) -------------------
__global__ __launch_bounds__(64) void k_reduce5(const float* __restrict__ pnum,
                                                const float* __restrict__ ppi,
                                                float* __restrict__ theta,
                                                uint16_t* __restrict__ lqf,
                                                float* __restrict__ logpi){
  const int G = 64;
  int w = blockIdx.x;              // b*K + k
  int lane = threadIdx.x;
  int b = w >> 4, k = w & 15;
  float4 sum = make_float4(0.f, 0.f, 0.f, 0.f);
  const float4* base = (const float4*)pnum + ((size_t)b * G * KK + k) * (DD/4) + lane;
  #pragma unroll 4
  for (int g = 0; g < G; ++g){
    float4 t = base[(size_t)g * KK * (DD/4)];
    sum.x += t.x; sum.y += t.y; sum.z += t.z; sum.w += t.w;
  }
  float ps = 0.f;
  for (int g = lane; g < G; g += 64) ps += ppi[((size_t)b * G + g) * KK + k];
  ps = wsum(ps);
  float inv = frcp(ps + EPSV);
  float4 th = make_float4(sum.x * inv, sum.y * inv, sum.z * inv, sum.w * inv);
  ((float4*)(theta + (size_t)w * DD))[lane] = th;
  float m = wmax(fmaxf(fmaxf(th.x, th.y), fmaxf(th.z, th.w)));
  float s = wsum(__expf(th.x-m) + __expf(th.y-m) + __expf(th.z-m) + __expf(th.w-m));
  float L = m + __logf(s);
  int d0 = lane * 4;
  int ss = d0 >> 5;
  int l2 = (((d0 & 31) >> 3) << 4) + k;
  int jb = d0 & 7;
  uint2 o;
  o.x = pk2(th.x - L + LOG256, th.y - L + LOG256);
  o.y = pk2(th.z - L + LOG256, th.w - L + LOG256);
  *(uint2*)(lqf + ((((size_t)b * 8 + ss) * 64 + l2) * 8 + jb)) = o;
  if (lane == 0) logpi[w] = __logf(ps * (1.0f / NN) + EPSV);
}

// ======================= OLD (fallback) PATH ===============================

__global__ __launch_bounds__(256) void k_rowstats(const float* __restrict__ x,
                                                  float2* __restrict__ stats){
  int row  = blockIdx.x * 4 + (threadIdx.x >> 6);
  int lane = threadIdx.x & 63;
  const float4* xr = (const float4*)(x + (size_t)row * DD);
  float4 v = xr[lane];
  float m = wmax(fmaxf(fmaxf(v.x, v.y), fmaxf(v.z, v.w)));
  float s = wsum(__expf(v.x-m) + __expf(v.y-m) + __expf(v.z-m) + __expf(v.w-m));
  if (lane == 0) stats[row] = make_float2(m, frcp(s));
}

__global__ __launch_bounds__(256) void k_initparams(const float* __restrict__ slot_logits,
                                                    const float* __restrict__ mix,
                                                    float* __restrict__ logq,
                                                    float* __restrict__ logpi){
  int w    = blockIdx.x * 4 + (threadIdx.x >> 6);
  int lane = threadIdx.x & 63;
  int k = w & 15;
  const float4* sl = (const float4*)(slot_logits + (size_t)k * DD);
  float4 t = sl[lane];
  float m = wmax(fmaxf(fmaxf(t.x, t.y), fmaxf(t.z, t.w)));
  float s = wsum(__expf(t.x-m) + __expf(t.y-m) + __expf(t.z-m) + __expf(t.w-m));
  float L = m + __logf(s);
  ((float4*)(logq + (size_t)w * DD))[lane] = make_float4(t.x-L, t.y-L, t.z-L, t.w-L);
  if (lane == 0) logpi[w] = __logf(mix[k] + EPSV);
}

__device__ __forceinline__ void stage4(const float* __restrict__ xb, int n0,
                                       int wave, int lane, float* dstbase){
  #pragma unroll
  for (int r = 0; r < 4; ++r){
    int row = wave * 4 + r;
    const float* gp = xb + (size_t)(n0 + row) * DD + lane * 4;
    float* lp = dstbase + row * DD;
    __builtin_amdgcn_global_load_lds(
        (const __attribute__((address_space(1))) unsigned int*)gp,
        (__attribute__((address_space(3))) unsigned int*)lp, 16, 0, 0);
  }
}

__global__ __launch_bounds__(256, 2) void k_em4(const float* __restrict__ x,
                                                const float2* __restrict__ stats,
                                                const float* __restrict__ logq,
                                                const float* __restrict__ logpi,
                                                float* __restrict__ pnum,
                                                float* __restrict__ ppi, int G){
  __shared__ float xl[2][16 * DD];
  __shared__ float pl[16 * DD];
  __shared__ float spi2[16];
  const int b = blockIdx.y, g = blockIdx.x;
  const int tid  = threadIdx.x;
  const int wave = __builtin_amdgcn_readfirstlane(tid >> 6);
  const int lane = tid & 63;
  const int rows_pb = NN / G;
  const int tiles   = rows_pb / 16;
  const int n00     = g * rows_pb;
  const float*  xb  = x + (size_t)b * NN * DD;
  const float2* stb = stats + (size_t)b * NN;
  const float4* lq4 = (const float4*)(logq + (size_t)b * KK * DD);
  float4 q[KK];
  #pragma unroll
  for (int k = 0; k < KK; ++k) q[k] = lq4[k * (DD/4) + lane];
  const float lpik = logpi[b * KK + (lane & 15)];
  float acc4[KK][4];
  #pragma unroll
  for (int k = 0; k < KK; ++k){ acc4[k][0]=0.f; acc4[k][1]=0.f; acc4[k][2]=0.f; acc4[k][3]=0.f; }
  float piacc = 0.f;
  stage4(xb, n00, wave, lane, &xl[0][0]);
  for (int t = 0; t < tiles; ++t){
    const int n0  = n00 + t * 16;
    const int cur = t & 1;
    float* xcur = &xl[cur][0];
    asm volatile("s_waitcnt vmcnt(0)" ::: "memory");
    __builtin_amdgcn_sched_barrier(0);
    if (t + 1 < tiles) stage4(xb, n0 + 16, wave, lane, &xl[cur ^ 1][0]);
    #pragma unroll
    for (int r = 0; r < 4; ++r){
      const int row = wave * 4 + r;
      float2 st = stb[n0 + row];
      #pragma unroll
      for (int c = 0; c < 4; ++c){
        float v = xcur[row * DD + c * 64 + lane];
        pl[row * DD + c * 64 + lane] = __expf(v - st.x) * st.y;
      }
    }
    float tg[4];
    #pragma unroll
    for (int r = 0; r < 4; ++r){
      const int row = wave * 4 + r;
      float4 p4 = *(const float4*)&pl[row * DD + lane * 4];
      float v[KK];
      #pragma unroll
      for (int k = 0; k < KK; ++k)
        v[k] = fmaf(p4.w, q[k].w, fmaf(p4.z, q[k].z, fmaf(p4.y, q[k].y, p4.x * q[k].x)));
      { bool up = (lane & 8) != 0;
        #pragma unroll
        for (int j = 0; j < 8; ++j){
          float lo = v[j], hi = v[j+8];
          float recv = __shfl_xor(up ? lo : hi, 8, 64);
          v[j] = (up ? hi : lo) + recv; } }
      { bool up = (lane & 4) != 0;
        #pragma unroll
        for (int j = 0; j < 4; ++j){
          float lo = v[j], hi = v[j+4];
          float recv = __shfl_xor(up ? lo : hi, 4, 64);
          v[j] = (up ? hi : lo) + recv; } }
      { bool up = (lane & 2) != 0;
        #pragma unroll
        for (int j = 0; j < 2; ++j){
          float lo = v[j], hi = v[j+2];
          float recv = __shfl_xor(up ? lo : hi, 2, 64);
          v[j] = (up ? hi : lo) + recv; } }
      { bool up = (lane & 1) != 0;
        float lo = v[0], hi = v[1];
        float recv = __shfl_xor(up ? lo : hi, 1, 64);
        v[0] = (up ? hi : lo) + recv; }
      float T = v[0];
      T += __shfl_xor(T, 16, 64);
      T += __shfl_xor(T, 32, 64);
      float lg = T + lpik;
      float mx = lg;
      #pragma unroll
      for (int m = 1; m <= 8; m <<= 1) mx = fmaxf(mx, __shfl_xor(mx, m, 64));
      float e = __expf(lg - mx);
      float s = e;
      #pragma unroll
      for (int m = 1; m <= 8; m <<= 1) s += __shfl_xor(s, m, 64);
      tg[r] = e * frcp(s);
      piacc += tg[r];
    }
    #pragma unroll
    for (int r = 0; r < 4; ++r){
      const int row = wave * 4 + r;
      float xv0 = xcur[row * DD +   0 + lane];
      float xv1 = xcur[row * DD +  64 + lane];
      float xv2 = xcur[row * DD + 128 + lane];
      float xv3 = xcur[row * DD + 192 + lane];
      #pragma unroll
      for (int k2 = 0; k2 < KK; ++k2){
        float gk = rdlane(tg[r], k2);
        acc4[k2][0] = fmaf(gk, xv0, acc4[k2][0]);
        acc4[k2][1] = fmaf(gk, xv1, acc4[k2][1]);
        acc4[k2][2] = fmaf(gk, xv2, acc4[k2][2]);
        acc4[k2][3] = fmaf(gk, xv3, acc4[k2][3]);
      }
    }
  }
  __syncthreads();
  float* sred = &xl[0][0];
  if (wave == 0){
    #pragma unroll
    for (int k2 = 0; k2 < KK; ++k2)
      #pragma unroll
      for (int c = 0; c < 4; ++c)
        sred[k2 * DD + c * 64 + lane] = acc4[k2][c];
    if (lane < KK) spi2[lane] = piacc;
  }
  __syncthreads();
  for (int w = 1; w < 4; ++w){
    if (wave == w){
      #pragma unroll
      for (int k2 = 0; k2 < KK; ++k2)
        #pragma unroll
        for (int c = 0; c < 4; ++c)
          sred[k2 * DD + c * 64 + lane] += acc4[k2][c];
      if (lane < KK) spi2[lane] += piacc;
    }
    __syncthreads();
  }
  float4* dst4 = (float4*)(pnum + (size_t)(b * G + g) * KK * DD);
  const float4* s4 = (const float4*)sred;
  #pragma unroll
  for (int j = 0; j < 4; ++j) dst4[tid + j * 256] = s4[tid + j * 256];
  if (tid < KK) ppi[(size_t)(b * G + g) * KK + tid] = spi2[tid];
}

__global__ __launch_bounds__(64) void k_reduce(const float* __restrict__ pnum,
                                               const float* __restrict__ ppi,
                                               float* __restrict__ theta,
                                               float* __restrict__ logq,
                                               float* __restrict__ logpi, int G){
  int w = blockIdx.x;
  int lane = threadIdx.x;
  int b = w >> 4, k = w & 15;
  float4 sum = make_float4(0.f, 0.f, 0.f, 0.f);
  const float4* base = (const float4*)pnum + ((size_t)b * G * KK + k) * (DD/4) + lane;
  #pragma unroll 4
  for (int g = 0; g < G; ++g){
    float4 t = base[(size_t)g * KK * (DD/4)];
    sum.x += t.x; sum.y += t.y; sum.z += t.z; sum.w += t.w;
  }
  float ps = 0.f;
  for (int g = lane; g < G; g += 64) ps += ppi[((size_t)b * G + g) * KK + k];
  ps = wsum(ps);
  float inv = frcp(ps + EPSV);
  float4 th = make_float4(sum.x * inv, sum.y * inv, sum.z * inv, sum.w * inv);
  ((float4*)(theta + (size_t)w * DD))[lane] = th;
  float m = wmax(fmaxf(fmaxf(th.x, th.y), fmaxf(th.z, th.w)));
  float s = wsum(__expf(th.x-m) + __expf(th.y-m) + __expf(th.z-m) + __expf(th.w-m));
  float L = m + __logf(s);
  ((float4*)(logq + (size_t)w * DD))[lane] = make_float4(th.x-L, th.y-L, th.z-L, th.w-L);
  if (lane == 0) logpi[w] = __logf(ps * (1.0f / NN) + EPSV);
}

// ======================= shared epilogue ===================================

__device__ __forceinline__ uint32_t rotl32(uint32_t x, int r){ return (x << r) | (x >> (32 - r)); }
__device__ __forceinline__ void tf2x32(uint32_t k0, uint32_t k1, uint32_t c0, uint32_t c1,
                                       uint32_t& o0, uint32_t& o1){
  uint32_t ks0 = k0, ks1 = k1, ks2 = 0x1BD11BDAu ^ k0 ^ k1;
  uint32_t x0 = c0 + ks0, x1 = c1 + ks1;
  #define RND(r) { x0 += x1; x1 = rotl32(x1, r); x1 ^= x0; }
  RND(13) RND(15) RND(26) RND(6)   x0 += ks1; x1 += ks2 + 1u;
  RND(17) RND(29) RND(16) RND(24)  x0 += ks2; x1 += ks0 + 2u;
  RND(13) RND(15) RND(26) RND(6)   x0 += ks0; x1 += ks1 + 3u;
  RND(17) RND(29) RND(16) RND(24)  x0 += ks1; x1 += ks2 + 4u;
  RND(13) RND(15) RND(26) RND(6)   x0 += ks2; x1 += ks0 + 5u;
  #undef RND
  o0 = x0; o1 = x1;
}

__global__ __launch_bounds__(256) void k_final(const float* __restrict__ theta,
                                               float* __restrict__ out){
  int w    = blockIdx.x * 4 + (threadIdx.x >> 6);
  int lane = threadIdx.x & 63;
  float4 th = ((const float4*)(theta + (size_t)w * DD))[lane];
  int i0 = w * DD + lane * 4;
  float gv[4];
  #pragma unroll
  for (int j = 0; j < 4; ++j){
    uint32_t i = (uint32_t)(i0 + j);
    uint32_t o0, o1;
    tf2x32(0u, 1u, 0u, i, o0, o1);
    uint32_t bits = o0 ^ o1;            // partitionable <=32-bit: bits1 ^ bits2
    float f = __uint_as_float((bits >> 9) | 0x3f800000u) - 1.0f;
    const float TINY = 1.17549435e-38f;
    float u = fmaxf(f + TINY, TINY);
    gv[j] = -logf(-logf(u));
  }
  float4 y = make_float4(th.x + gv[0], th.y + gv[1], th.z + gv[2], th.w + gv[3]);
  float m = wmax(fmaxf(fmaxf(y.x, y.y), fmaxf(y.z, y.w)));
  float4 e = make_float4(__expf(y.x-m), __expf(y.y-m), __expf(y.z-m), __expf(y.w-m));
  float s = wsum(e.x + e.y + e.z + e.w);
  float inv = 1.0f / s;
  ((float4*)(out + (size_t)w * DD))[lane] =
      make_float4(e.x*inv, e.y*inv, e.z*inv, e.w*inv);
}

__global__ __launch_bounds__(256) void k_fill(float* __restrict__ out, float v){
  out[blockIdx.x * 256 + threadIdx.x] = v;
}

extern "C" void kernel_launch(void* const* d_in, const int* in_sizes, int n_in,
                              void* d_out, int out_size, void* d_ws, size_t ws_size,
                              hipStream_t stream){
  const float* x    = (const float*)d_in[0];
  const float* sl   = (const float*)d_in[1];
  const float* mix  = (const float*)d_in[2];
  float* out = (float*)d_out;
  char* ws = (char*)d_ws;

  const size_t SZ_PBF  = 67108864ull;              // 8*1024*8*64*16
  const size_t SZ_XBF  = 67108864ull;              // 8*512*16*64*16
  const size_t SZ_LQF  = 65536ull;                 // 8*8*64*8*2
  const size_t SZ_TH   = (size_t)BN*KK*DD*4;       // 131072
  const size_t SZ_LP   = 512ull;
  const size_t SZ_PNUM = (size_t)BN*64*KK*DD*4;    // 33554432
  const size_t SZ_PPI  = (size_t)BN*64*KK*4;
  size_t need_new = SZ_PBF + SZ_XBF + SZ_LQF + SZ_TH + SZ_LP + SZ_PNUM + SZ_PPI;

  if (ws_size >= need_new){
    size_t o = 0;
    uint4*    pbf   = (uint4*)(ws + o);     o += SZ_PBF;
    uint4*    xbf   = (uint4*)(ws + o);     o += SZ_XBF;
    uint16_t* lqf   = (uint16_t*)(ws + o);  o += SZ_LQF;
    float*    theta = (float*)(ws + o);     o += SZ_TH;
    float*    logpi = (float*)(ws + o);     o += SZ_LP;
    float*    pnum  = (float*)(ws + o);     o += SZ_PNUM;
    float*    ppi   = (float*)(ws + o);

    k_prep <<<dim3(512, BN), 256, 0, stream>>>(x, pbf, xbf);
    k_init5<<<(BN*KK)/4, 256, 0, stream>>>(sl, mix, lqf, logpi);
    for (int it = 0; it < NITER; ++it){
      k_em5    <<<dim3(64, BN), 256, 0, stream>>>(pbf, xbf, (const uint4*)lqf,
                                                  logpi, pnum, ppi);
      k_reduce5<<<BN*KK, 64, 0, stream>>>(pnum, ppi, theta, lqf, logpi);
    }
    k_final<<<(BN*KK)/4, 256, 0, stream>>>(theta, out);
    return;
  }

  // -------- fallback: r9-verified path --------
  float* wsf = (float*)d_ws;
  int G = 64;
  size_t need = 0;
  for (;; G >>= 1){
    need = ((size_t)2*BN*NN + 2*(size_t)BN*KK*DD + BN*KK
            + (size_t)BN*G*KK*DD + (size_t)BN*G*KK) * sizeof(float);
    if (need <= ws_size || G == 8) break;
  }
  if (need > ws_size){
    k_fill<<<(BN*KK*DD)/256, 256, 0, stream>>>(out, -9.0f);
    return;
  }
  size_t o = 0;
  float2* stats = (float2*)wsf;           o += (size_t)2*BN*NN;
  float*  logq  = wsf + o;                o += (size_t)BN*KK*DD;
  float*  theta = wsf + o;                o += (size_t)BN*KK*DD;
  float*  logpi = wsf + o;                o += (size_t)BN*KK;
  float*  pnum  = wsf + o;                o += (size_t)BN*G*KK*DD;
  float*  ppi   = wsf + o;

  k_rowstats  <<<BN*NN/4, 256, 0, stream>>>(x, stats);
  k_initparams<<<(BN*KK)/4, 256, 0, stream>>>(sl, mix, logq, logpi);
  for (int it = 0; it < NITER; ++it){
    k_em4   <<<dim3(G, BN), 256, 0, stream>>>(x, stats, logq, logpi, pnum, ppi, G);
    k_reduce<<<BN*KK, 64, 0, stream>>>(pnum, ppi, theta, logq, logpi, G);
  }
  k_final<<<(BN*KK)/4, 256, 0, stream>>>(theta, out);
}

// Round 11
// 209.178 us; speedup vs baseline: 2.9336x; 1.0090x over previous
//
#include <hip/hip_runtime.h>
#include <cstdint>
#include <cstddef>

#define BN 8
#define NN 16384
#define DD 256
#define KK 16
#define NITER 5
#define EPSV 1e-8f
#define LOG256 5.545177444479562f
#define PSTR 260   // words; 260*4=1040 B (16B-aligned rows), mod-128 = 4 -> bank rotate

typedef short bf16x8 __attribute__((ext_vector_type(8)));
typedef float f32x4 __attribute__((ext_vector_type(4)));

__device__ __forceinline__ float frcp(float x){ return __builtin_amdgcn_rcpf(x); }
__device__ __forceinline__ float rdlane(float v, int l){
  return __int_as_float(__builtin_amdgcn_readlane(__float_as_int(v), l));
}
__device__ __forceinline__ float wmax(float v){
  #pragma unroll
  for (int m = 32; m >= 1; m >>= 1) v = fmaxf(v, __shfl_xor(v, m, 64));
  return v;
}
__device__ __forceinline__ float wsum(float v){
  #pragma unroll
  for (int m = 32; m >= 1; m >>= 1) v += __shfl_xor(v, m, 64);
  return v;
}
__device__ __forceinline__ uint32_t f2bf(float f){   // RNE f32->bf16
  uint32_t u = __float_as_uint(f);
  return (u + 0x7fffu + ((u >> 16) & 1u)) >> 16;
}
__device__ __forceinline__ uint32_t pk2(float a, float b){
  return f2bf(a) | (f2bf(b) << 16);
}

// ======================= MFMA PATH =========================================

// ---- prologue: row stats + emit pbf (A-frags) and xbf (B-frags) -----------
// pbf: [b][chunk=2S+c][s=8][lane][8bf16]; element j: p_norm[n][32s+8(l>>4)+j],
//      n = 8*(rho>>2) + 4c + (rho&3), rho = lane&15 (row-interleaved chunks)
// xbf: [b][S][dt=16][lane][8bf16]; element j: x[8*(l>>4)+j][16dt + (lane&15)]
__global__ __launch_bounds__(256, 4) void k_prep(const float* __restrict__ x,
                                                 uint4* __restrict__ pbf,
                                                 uint4* __restrict__ xbf){
  __shared__ float xs[32 * PSTR];
  __shared__ float sm[32], si[32];
  const int b = blockIdx.y, S = blockIdx.x;          // S: 0..511
  const int tid = threadIdx.x;
  const int wave = tid >> 6, lane = tid & 63;
  const float* xb = x + ((size_t)b * NN + (size_t)S * 32) * DD;

  #pragma unroll
  for (int r = 0; r < 8; ++r){
    int row = wave * 8 + r;
    const float* gp = xb + (size_t)row * DD + lane * 4;
    float* lp = &xs[row * PSTR];                     // 16B-aligned (PSTR%4==0)
    __builtin_amdgcn_global_load_lds(
        (const __attribute__((address_space(1))) unsigned int*)gp,
        (__attribute__((address_space(3))) unsigned int*)lp, 16, 0, 0);
  }
  asm volatile("s_waitcnt vmcnt(0)" ::: "memory");
  #pragma unroll
  for (int r = 0; r < 8; ++r){
    int row = wave * 8 + r;
    float4 v = *(const float4*)&xs[row * PSTR + lane * 4];
    float m = wmax(fmaxf(fmaxf(v.x, v.y), fmaxf(v.z, v.w)));
    float s = wsum(__expf(v.x-m) + __expf(v.y-m) + __expf(v.z-m) + __expf(v.w-m));
    if (lane == 0){ sm[row] = m; si[row] = frcp(s); }
  }
  __syncthreads();

  // pbf: wave handles 4 (c,s) pairs
  #pragma unroll
  for (int i = 0; i < 4; ++i){
    int p = wave * 4 + i; int c = p >> 3, s = p & 7;
    int rho = lane & 15;
    int n = 8 * (rho >> 2) + 4 * c + (rho & 3);
    int d = 32 * s + 8 * (lane >> 4);
    float m = sm[n], inv = si[n];
    float4 v0 = *(const float4*)&xs[n * PSTR + d];
    float4 v1 = *(const float4*)&xs[n * PSTR + d + 4];
    uint4 o;
    o.x = pk2(__expf(v0.x-m)*inv, __expf(v0.y-m)*inv);
    o.y = pk2(__expf(v0.z-m)*inv, __expf(v0.w-m)*inv);
    o.z = pk2(__expf(v1.x-m)*inv, __expf(v1.y-m)*inv);
    o.w = pk2(__expf(v1.z-m)*inv, __expf(v1.w-m)*inv);
    pbf[(((size_t)b * 1024 + (size_t)S * 2 + c) * 8 + s) * 64 + lane] = o;
  }
  // xbf: wave handles 4 dtiles
  #pragma unroll
  for (int i = 0; i < 4; ++i){
    int dt = wave * 4 + i;
    int col = dt * 16 + (lane & 15);
    int g2 = lane >> 4;
    float v[8];
    #pragma unroll
    for (int j = 0; j < 8; ++j) v[j] = xs[(8 * g2 + j) * PSTR + col];
    uint4 o;
    o.x = pk2(v[0], v[1]); o.y = pk2(v[2], v[3]);
    o.z = pk2(v[4], v[5]); o.w = pk2(v[6], v[7]);
    xbf[(((size_t)b * 512 + S) * 16 + dt) * 64 + lane] = o;
  }
}

// ---- init: logq B-frags (resid = logsoftmax + log256, bf16) + logpi -------
__global__ __launch_bounds__(256) void k_init5(const float* __restrict__ slot_logits,
                                               const float* __restrict__ mix,
                                               uint16_t* __restrict__ lqf,
                                               float* __restrict__ logpi){
  int w    = blockIdx.x * 4 + (threadIdx.x >> 6);   // b*K + k
  int lane = threadIdx.x & 63;
  int b = w >> 4, k = w & 15;
  const float4* sl = (const float4*)(slot_logits + (size_t)k * DD);
  float4 t = sl[lane];
  float m = wmax(fmaxf(fmaxf(t.x, t.y), fmaxf(t.z, t.w)));
  float s = wsum(__expf(t.x-m) + __expf(t.y-m) + __expf(t.z-m) + __expf(t.w-m));
  float L = m + __logf(s);
  int d0 = lane * 4;
  int ss = d0 >> 5;
  int l2 = (((d0 & 31) >> 3) << 4) + k;
  int jb = d0 & 7;
  uint2 o;
  o.x = pk2(t.x - L + LOG256, t.y - L + LOG256);
  o.y = pk2(t.z - L + LOG256, t.w - L + LOG256);
  *(uint2*)(lqf + ((((size_t)b * 8 + ss) * 64 + l2) * 8 + jb)) = o;
  if (lane == 0) logpi[w] = __logf(mix[k] + EPSV);
}

// ---- fused EM iteration via MFMA ------------------------------------------
__global__ __launch_bounds__(256, 2) void k_em5(const uint4* __restrict__ pbf,
                                                const uint4* __restrict__ xbf,
                                                const uint4* __restrict__ lqf,
                                                const float* __restrict__ logpi,
                                                float* __restrict__ pnum,
                                                float* __restrict__ ppi){
  __shared__ float sred[KK * DD];
  __shared__ float spi2[16];
  const int b = blockIdx.y, g = blockIdx.x;          // g: 0..63
  const int tid = threadIdx.x;
  const int wave = tid >> 6, lane = tid & 63;

  bf16x8 lqv[8];
  {
    const uint4* p = lqf + (size_t)b * 8 * 64 + lane;
    #pragma unroll
    for (int s = 0; s < 8; ++s){ uint4 t = p[s * 64]; lqv[s] = *(bf16x8*)&t; }
  }
  const float lpik = logpi[b * KK + (lane & 15)];

  f32x4 acc[16];
  #pragma unroll
  for (int dt = 0; dt < 16; ++dt) acc[dt] = (f32x4){0.f, 0.f, 0.f, 0.f};
  float piacc = 0.f;

  const int S0 = (g * 4 + wave) * 2;
  #pragma unroll
  for (int ssi = 0; ssi < 2; ++ssi){
    const int S = S0 + ssi;
    const uint4* pb = pbf + (((size_t)b * 1024 + (size_t)S * 2) * 8) * 64 + lane;
    const uint4* xr = xbf + (((size_t)b * 512 + S) * 16) * 64 + lane;

    uint4 pa[16];
    #pragma unroll
    for (int i = 0; i < 16; ++i) pa[i] = pb[(size_t)i * 64];   // [c*8+s]

    float ga[8];
    #pragma unroll
    for (int c = 0; c < 2; ++c){
      f32x4 lc = (f32x4){0.f, 0.f, 0.f, 0.f};
      #pragma unroll
      for (int s = 0; s < 8; ++s){
        bf16x8 a = *(bf16x8*)&pa[c * 8 + s];
        lc = __builtin_amdgcn_mfma_f32_16x16x32_bf16(a, lqv[s], lc, 0, 0, 0);
      }
      #pragma unroll
      for (int r2 = 0; r2 < 4; ++r2){
        float lg = lc[r2] + lpik;
        float mx = lg;
        #pragma unroll
        for (int m = 1; m <= 8; m <<= 1) mx = fmaxf(mx, __shfl_xor(mx, m, 64));
        float e = __expf(lg - mx);
        float s2 = e;
        #pragma unroll
        for (int m = 1; m <= 8; m <<= 1) s2 += __shfl_xor(s2, m, 64);
        float gv = e * frcp(s2);
        ga[c * 4 + r2] = gv;
        piacc += gv;
      }
    }
    uint4 gp;
    gp.x = pk2(ga[0], ga[1]); gp.y = pk2(ga[2], ga[3]);
    gp.z = pk2(ga[4], ga[5]); gp.w = pk2(ga[6], ga[7]);
    bf16x8 gA = *(bf16x8*)&gp;
    #pragma unroll
    for (int dt = 0; dt < 16; ++dt){
      uint4 xv = xr[(size_t)dt * 64];
      bf16x8 xB = *(bf16x8*)&xv;
      acc[dt] = __builtin_amdgcn_mfma_f32_16x16x32_bf16(gA, xB, acc[dt], 0, 0, 0);
    }
  }

  // epilogue: cross-wave reduce
  float pk = piacc;
  pk += __shfl_xor(pk, 16, 64);
  pk += __shfl_xor(pk, 32, 64);
  __syncthreads();
  if (wave == 0){
    #pragma unroll
    for (int dt = 0; dt < 16; ++dt)
      #pragma unroll
      for (int r2 = 0; r2 < 4; ++r2)
        sred[(4 * (lane >> 4) + r2) * DD + dt * 16 + (lane & 15)] = acc[dt][r2];
    if (lane < 16) spi2[lane] = pk;
  }
  __syncthreads();
  for (int w = 1; w < 4; ++w){
    if (wave == w){
      #pragma unroll
      for (int dt = 0; dt < 16; ++dt)
        #pragma unroll
        for (int r2 = 0; r2 < 4; ++r2)
          sred[(4 * (lane >> 4) + r2) * DD + dt * 16 + (lane & 15)] += acc[dt][r2];
      if (lane < 16) spi2[lane] += pk;
    }
    __syncthreads();
  }
  float4* dst4 = (float4*)(pnum + (size_t)(b * 64 + g) * KK * DD);
  const float4* s4 = (const float4*)sred;
  #pragma unroll
  for (int j = 0; j < 4; ++j) dst4[tid + j * 256] = s4[tid + j * 256];
  if (tid < 16) ppi[(size_t)(b * 64 + g) * KK + tid] = spi2[tid];
}

// ---- reduce partials -> theta, lqf frags, log_pi (G=64) -------------------
__global__ __launch_bounds__(64) void k_reduce5(const float* __restrict__ pnum,
                                                const float* __restrict__ ppi,
                                                float* __restrict__ theta,
                                                uint16_t* __restrict__ lqf,
                                                float* __restrict__ logpi){
  const int G = 64;
  int w = blockIdx.x;              // b*K + k
  int lane = threadIdx.x;
  int b = w >> 4, k = w & 15;
  float4 sum = make_float4(0.f, 0.f, 0.f, 0.f);
  const float4* base = (const float4*)pnum + ((size_t)b * G * KK + k) * (DD/4) + lane;
  #pragma unroll 4
  for (int g = 0; g < G; ++g){
    float4 t = base[(size_t)g * KK * (DD/4)];
    sum.x += t.x; sum.y += t.y; sum.z += t.z; sum.w += t.w;
  }
  float ps = 0.f;
  for (int g = lane; g < G; g += 64) ps += ppi[((size_t)b * G + g) * KK + k];
  ps = wsum(ps);
  float inv = frcp(ps + EPSV);
  float4 th = make_float4(sum.x * inv, sum.y * inv, sum.z * inv, sum.w * inv);
  ((float4*)(theta + (size_t)w * DD))[lane] = th;
  float m = wmax(fmaxf(fmaxf(th.x, th.y), fmaxf(th.z, th.w)));
  float s = wsum(__expf(th.x-m) + __expf(th.y-m) + __expf(th.z-m) + __expf(th.w-m));
  float L = m + __logf(s);
  int d0 = lane * 4;
  int ss = d0 >> 5;
  int l2 = (((d0 & 31) >> 3) << 4) + k;
  int jb = d0 & 7;
  uint2 o;
  o.x = pk2(th.x - L + LOG256, th.y - L + LOG256);
  o.y = pk2(th.z - L + LOG256, th.w - L + LOG256);
  *(uint2*)(lqf + ((((size_t)b * 8 + ss) * 64 + l2) * 8 + jb)) = o;
  if (lane == 0) logpi[w] = __logf(ps * (1.0f / NN) + EPSV);
}

// ======================= shared epilogue ===================================

__device__ __forceinline__ uint32_t rotl32(uint32_t x, int r){ return (x << r) | (x >> (32 - r)); }
__device__ __forceinline__ void tf2x32(uint32_t k0, uint32_t k1, uint32_t c0, uint32_t c1,
                                       uint32_t& o0, uint32_t& o1){
  uint32_t ks0 = k0, ks1 = k1, ks2 = 0x1BD11BDAu ^ k0 ^ k1;
  uint32_t x0 = c0 + ks0, x1 = c1 + ks1;
  #define RND(r) { x0 += x1; x1 = rotl32(x1, r); x1 ^= x0; }
  RND(13) RND(15) RND(26) RND(6)   x0 += ks1; x1 += ks2 + 1u;
  RND(17) RND(29) RND(16) RND(24)  x0 += ks2; x1 += ks0 + 2u;
  RND(13) RND(15) RND(26) RND(6)   x0 += ks0; x1 += ks1 + 3u;
  RND(17) RND(29) RND(16) RND(24)  x0 += ks1; x1 += ks2 + 4u;
  RND(13) RND(15) RND(26) RND(6)   x0 += ks2; x1 += ks0 + 5u;
  #undef RND
  o0 = x0; o1 = x1;
}

__global__ __launch_bounds__(256) void k_final(const float* __restrict__ theta,
                                               float* __restrict__ out){
  int w    = blockIdx.x * 4 + (threadIdx.x >> 6);
  int lane = threadIdx.x & 63;
  float4 th = ((const float4*)(theta + (size_t)w * DD))[lane];
  int i0 = w * DD + lane * 4;
  float gv[4];
  #pragma unroll
  for (int j = 0; j < 4; ++j){
    uint32_t i = (uint32_t)(i0 + j);
    uint32_t o0, o1;
    tf2x32(0u, 1u, 0u, i, o0, o1);
    uint32_t bits = o0 ^ o1;            // partitionable <=32-bit: bits1 ^ bits2
    float f = __uint_as_float((bits >> 9) | 0x3f800000u) - 1.0f;
    const float TINY = 1.17549435e-38f;
    float u = fmaxf(f + TINY, TINY);
    gv[j] = -logf(-logf(u));
  }
  float4 y = make_float4(th.x + gv[0], th.y + gv[1], th.z + gv[2], th.w + gv[3]);
  float m = wmax(fmaxf(fmaxf(y.x, y.y), fmaxf(y.z, y.w)));
  float4 e = make_float4(__expf(y.x-m), __expf(y.y-m), __expf(y.z-m), __expf(y.w-m));
  float s = wsum(e.x + e.y + e.z + e.w);
  float inv = 1.0f / s;
  ((float4*)(out + (size_t)w * DD))[lane] =
      make_float4(e.x*inv, e.y*inv, e.z*inv, e.w*inv);
}

__global__ __launch_bounds__(256) void k_fill(float* __restrict__ out, float v){
  out[blockIdx.x * 256 + threadIdx.x] = v;
}

// ======================= fallback path (r9-verified) =======================

__global__ __launch_bounds__(256) void k_rowstats(const float* __restrict__ x,
                                                  float2* __restrict__ stats){
  int row  = blockIdx.x * 4 + (threadIdx.x >> 6);
  int lane = threadIdx.x & 63;
  const float4* xr = (const float4*)(x + (size_t)row * DD);
  float4 v = xr[lane];
  float m = wmax(fmaxf(fmaxf(v.x, v.y), fmaxf(v.z, v.w)));
  float s = wsum(__expf(v.x-m) + __expf(v.y-m) + __expf(v.z-m) + __expf(v.w-m));
  if (lane == 0) stats[row] = make_float2(m, frcp(s));
}

__global__ __launch_bounds__(256) void k_initparams(const float* __restrict__ slot_logits,
                                                    const float* __restrict__ mix,
                                                    float* __restrict__ logq,
                                                    float* __restrict__ logpi){
  int w    = blockIdx.x * 4 + (threadIdx.x >> 6);
  int lane = threadIdx.x & 63;
  int k = w & 15;
  const float4* sl = (const float4*)(slot_logits + (size_t)k * DD);
  float4 t = sl[lane];
  float m = wmax(fmaxf(fmaxf(t.x, t.y), fmaxf(t.z, t.w)));
  float s = wsum(__expf(t.x-m) + __expf(t.y-m) + __expf(t.z-m) + __expf(t.w-m));
  float L = m + __logf(s);
  ((float4*)(logq + (size_t)w * DD))[lane] = make_float4(t.x-L, t.y-L, t.z-L, t.w-L);
  if (lane == 0) logpi[w] = __logf(mix[k] + EPSV);
}

__device__ __forceinline__ void stage4(const float* __restrict__ xb, int n0,
                                       int wave, int lane, float* dstbase){
  #pragma unroll
  for (int r = 0; r < 4; ++r){
    int row = wave * 4 + r;
    const float* gp = xb + (size_t)(n0 + row) * DD + lane * 4;
    float* lp = dstbase + row * DD;
    __builtin_amdgcn_global_load_lds(
        (const __attribute__((address_space(1))) unsigned int*)gp,
        (__attribute__((address_space(3))) unsigned int*)lp, 16, 0, 0);
  }
}

__global__ __launch_bounds__(256, 2) void k_em4(const float* __restrict__ x,
                                                const float2* __restrict__ stats,
                                                const float* __restrict__ logq,
                                                const float* __restrict__ logpi,
                                                float* __restrict__ pnum,
                                                float* __restrict__ ppi, int G){
  __shared__ float xl[2][16 * DD];
  __shared__ float pl[16 * DD];
  __shared__ float spi2[16];
  const int b = blockIdx.y, g = blockIdx.x;
  const int tid  = threadIdx.x;
  const int wave = __builtin_amdgcn_readfirstlane(tid >> 6);
  const int lane = tid & 63;
  const int rows_pb = NN / G;
  const int tiles   = rows_pb / 16;
  const int n00     = g * rows_pb;
  const float*  xb  = x + (size_t)b * NN * DD;
  const float2* stb = stats + (size_t)b * NN;
  const float4* lq4 = (const float4*)(logq + (size_t)b * KK * DD);
  float4 q[KK];
  #pragma unroll
  for (int k = 0; k < KK; ++k) q[k] = lq4[k * (DD/4) + lane];
  const float lpik = logpi[b * KK + (lane & 15)];
  float acc4[KK][4];
  #pragma unroll
  for (int k = 0; k < KK; ++k){ acc4[k][0]=0.f; acc4[k][1]=0.f; acc4[k][2]=0.f; acc4[k][3]=0.f; }
  float piacc = 0.f;
  stage4(xb, n00, wave, lane, &xl[0][0]);
  for (int t = 0; t < tiles; ++t){
    const int n0  = n00 + t * 16;
    const int cur = t & 1;
    float* xcur = &xl[cur][0];
    asm volatile("s_waitcnt vmcnt(0)" ::: "memory");
    __builtin_amdgcn_sched_barrier(0);
    if (t + 1 < tiles) stage4(xb, n0 + 16, wave, lane, &xl[cur ^ 1][0]);
    #pragma unroll
    for (int r = 0; r < 4; ++r){
      const int row = wave * 4 + r;
      float2 st = stb[n0 + row];
      #pragma unroll
      for (int c = 0; c < 4; ++c){
        float v = xcur[row * DD + c * 64 + lane];
        pl[row * DD + c * 64 + lane] = __expf(v - st.x) * st.y;
      }
    }
    float tg[4];
    #pragma unroll
    for (int r = 0; r < 4; ++r){
      const int row = wave * 4 + r;
      float4 p4 = *(const float4*)&pl[row * DD + lane * 4];
      float v[KK];
      #pragma unroll
      for (int k = 0; k < KK; ++k)
        v[k] = fmaf(p4.w, q[k].w, fmaf(p4.z, q[k].z, fmaf(p4.y, q[k].y, p4.x * q[k].x)));
      { bool up = (lane & 8) != 0;
        #pragma unroll
        for (int j = 0; j < 8; ++j){
          float lo = v[j], hi = v[j+8];
          float recv = __shfl_xor(up ? lo : hi, 8, 64);
          v[j] = (up ? hi : lo) + recv; } }
      { bool up = (lane & 4) != 0;
        #pragma unroll
        for (int j = 0; j < 4; ++j){
          float lo = v[j], hi = v[j+4];
          float recv = __shfl_xor(up ? lo : hi, 4, 64);
          v[j] = (up ? hi : lo) + recv; } }
      { bool up = (lane & 2) != 0;
        #pragma unroll
        for (int j = 0; j < 2; ++j){
          float lo = v[j], hi = v[j+2];
          float recv = __shfl_xor(up ? lo : hi, 2, 64);
          v[j] = (up ? hi : lo) + recv; } }
      { bool up = (lane & 1) != 0;
        float lo = v[0], hi = v[1];
        float recv = __shfl_xor(up ? lo : hi, 1, 64);
        v[0] = (up ? hi : lo) + recv; }
      float T = v[0];
      T += __shfl_xor(T, 16, 64);
      T += __shfl_xor(T, 32, 64);
      float lg = T + lpik;
      float mx = lg;
      #pragma unroll
      for (int m = 1; m <= 8; m <<= 1) mx = fmaxf(mx, __shfl_xor(mx, m, 64));
      float e = __expf(lg - mx);
      float s = e;
      #pragma unroll
      for (int m = 1; m <= 8; m <<= 1) s += __shfl_xor(s, m, 64);
      tg[r] = e * frcp(s);
      piacc += tg[r];
    }
    #pragma unroll
    for (int r = 0; r < 4; ++r){
      const int row = wave * 4 + r;
      float xv0 = xcur[row * DD +   0 + lane];
      float xv1 = xcur[row * DD +  64 + lane];
      float xv2 = xcur[row * DD + 128 + lane];
      float xv3 = xcur[row * DD + 192 + lane];
      #pragma unroll
      for (int k2 = 0; k2 < KK; ++k2){
        float gk = rdlane(tg[r], k2);
        acc4[k2][0] = fmaf(gk, xv0, acc4[k2][0]);
        acc4[k2][1] = fmaf(gk, xv1, acc4[k2][1]);
        acc4[k2][2] = fmaf(gk, xv2, acc4[k2][2]);
        acc4[k2][3] = fmaf(gk, xv3, acc4[k2][3]);
      }
    }
  }
  __syncthreads();
  float* sred = &xl[0][0];
  if (wave == 0){
    #pragma unroll
    for (int k2 = 0; k2 < KK; ++k2)
      #pragma unroll
      for (int c = 0; c < 4; ++c)
        sred[k2 * DD + c * 64 + lane] = acc4[k2][c];
    if (lane < KK) spi2[lane] = piacc;
  }
  __syncthreads();
  for (int w = 1; w < 4; ++w){
    if (wave == w){
      #pragma unroll
      for (int k2 = 0; k2 < KK; ++k2)
        #pragma unroll
        for (int c = 0; c < 4; ++c)
          sred[k2 * DD + c * 64 + lane] += acc4[k2][c];
      if (lane < KK) spi2[lane] += piacc;
    }
    __syncthreads();
  }
  float4* dst4 = (float4*)(pnum + (size_t)(b * G + g) * KK * DD);
  const float4* s4 = (const float4*)sred;
  #pragma unroll
  for (int j = 0; j < 4; ++j) dst4[tid + j * 256] = s4[tid + j * 256];
  if (tid < KK) ppi[(size_t)(b * G + g) * KK + tid] = spi2[tid];
}

__global__ __launch_bounds__(64) void k_reduce(const float* __restrict__ pnum,
                                               const float* __restrict__ ppi,
                                               float* __restrict__ theta,
                                               float* __restrict__ logq,
                                               float* __restrict__ logpi, int G){
  int w = blockIdx.x;
  int lane = threadIdx.x;
  int b = w >> 4, k = w & 15;
  float4 sum = make_float4(0.f, 0.f, 0.f, 0.f);
  const float4* base = (const float4*)pnum + ((size_t)b * G * KK + k) * (DD/4) + lane;
  #pragma unroll 4
  for (int g = 0; g < G; ++g){
    float4 t = base[(size_t)g * KK * (DD/4)];
    sum.x += t.x; sum.y += t.y; sum.z += t.z; sum.w += t.w;
  }
  float ps = 0.f;
  for (int g = lane; g < G; g += 64) ps += ppi[((size_t)b * G + g) * KK + k];
  ps = wsum(ps);
  float inv = frcp(ps + EPSV);
  float4 th = make_float4(sum.x * inv, sum.y * inv, sum.z * inv, sum.w * inv);
  ((float4*)(theta + (size_t)w * DD))[lane] = th;
  float m = wmax(fmaxf(fmaxf(th.x, th.y), fmaxf(th.z, th.w)));
  float s = wsum(__expf(th.x-m) + __expf(th.y-m) + __expf(th.z-m) + __expf(th.w-m));
  float L = m + __logf(s);
  ((float4*)(logq + (size_t)w * DD))[lane] = make_float4(th.x-L, th.y-L, th.z-L, th.w-L);
  if (lane == 0) logpi[w] = __logf(ps * (1.0f / NN) + EPSV);
}

extern "C" void kernel_launch(void* const* d_in, const int* in_sizes, int n_in,
                              void* d_out, int out_size, void* d_ws, size_t ws_size,
                              hipStream_t stream){
  const float* x    = (const float*)d_in[0];
  const float* sl   = (const float*)d_in[1];
  const float* mix  = (const float*)d_in[2];
  float* out = (float*)d_out;
  char* ws = (char*)d_ws;

  const size_t SZ_PBF  = 67108864ull;              // 8*1024*8*64*16
  const size_t SZ_XBF  = 67108864ull;              // 8*512*16*64*16
  const size_t SZ_LQF  = 65536ull;                 // 8*8*64*8*2
  const size_t SZ_TH   = (size_t)BN*KK*DD*4;       // 131072
  const size_t SZ_LP   = 512ull;
  const size_t SZ_PNUM = (size_t)BN*64*KK*DD*4;    // 33554432
  const size_t SZ_PPI  = (size_t)BN*64*KK*4;
  size_t need_new = SZ_PBF + SZ_XBF + SZ_LQF + SZ_TH + SZ_LP + SZ_PNUM + SZ_PPI;

  if (ws_size >= need_new){
    size_t o = 0;
    uint4*    pbf   = (uint4*)(ws + o);     o += SZ_PBF;
    uint4*    xbf   = (uint4*)(ws + o);     o += SZ_XBF;
    uint16_t* lqf   = (uint16_t*)(ws + o);  o += SZ_LQF;
    float*    theta = (float*)(ws + o);     o += SZ_TH;
    float*    logpi = (float*)(ws + o);     o += SZ_LP;
    float*    pnum  = (float*)(ws + o);     o += SZ_PNUM;
    float*    ppi   = (float*)(ws + o);

    k_prep <<<dim3(512, BN), 256, 0, stream>>>(x, pbf, xbf);
    k_init5<<<(BN*KK)/4, 256, 0, stream>>>(sl, mix, lqf, logpi);
    for (int it = 0; it < NITER; ++it){
      k_em5    <<<dim3(64, BN), 256, 0, stream>>>(pbf, xbf, (const uint4*)lqf,
                                                  logpi, pnum, ppi);
      k_reduce5<<<BN*KK, 64, 0, stream>>>(pnum, ppi, theta, lqf, logpi);
    }
    k_final<<<(BN*KK)/4, 256, 0, stream>>>(theta, out);
    return;
  }

  // -------- fallback: r9-verified path --------
  float* wsf = (float*)d_ws;
  int G = 64;
  size_t need = 0;
  for (;; G >>= 1){
    need = ((size_t)2*BN*NN + 2*(size_t)BN*KK*DD + BN*KK
            + (size_t)BN*G*KK*DD + (size_t)BN*G*KK) * sizeof(float);
    if (need <= ws_size || G == 8) break;
  }
  if (need > ws_size){
    k_fill<<<(BN*KK*DD)/256, 256, 0, stream>>>(out, -9.0f);
    return;
  }
  size_t o = 0;
  float2* stats = (float2*)wsf;           o += (size_t)2*BN*NN;
  float*  logq  = wsf + o;                o += (size_t)BN*KK*DD;
  float*  theta = wsf + o;                o += (size_t)BN*KK*DD;
  float*  logpi = wsf + o;                o += (size_t)BN*KK;
  float*  pnum  = wsf + o;                o += (size_t)BN*G*KK*DD;
  float*  ppi   = wsf + o;

  k_rowstats  <<<BN*NN/4, 256, 0, stream>>>(x, stats);
  k_initparams<<<(BN*KK)/4, 256, 0, stream>>>(sl, mix, logq, logpi);
  for (int it = 0; it < NITER; ++it){
    k_em4   <<<dim3(G, BN), 256, 0, stream>>>(x, stats, logq, logpi, pnum, ppi, G);
    k_reduce<<<BN*KK, 64, 0, stream>>>(pnum, ppi, theta, logq, logpi, G);
  }
  k_final<<<(BN*KK)/4, 256, 0, stream>>>(theta, out);
}

// Round 12
// 160.176 us; speedup vs baseline: 3.8310x; 1.3059x over previous
//
#include <hip/hip_runtime.h>
#include <cstdint>
#include <cstddef>

#define BN 8
#define NN 16384
#define DD 256
#define KK 16
#define NITER 5
#define EPSV 1e-8f
#define LOG256 5.545177444479562f
#define PSTR 260   // LDS row stride (words); 1040 B, 16B-aligned
#define TPB 8      // S-tiles per k_prep block

typedef float f32x4 __attribute__((ext_vector_type(4)));
typedef long  i64v;

__device__ __forceinline__ float frcp(float x){ return __builtin_amdgcn_rcpf(x); }
__device__ __forceinline__ float wmax(float v){
  #pragma unroll
  for (int m = 32; m >= 1; m >>= 1) v = fmaxf(v, __shfl_xor(v, m, 64));
  return v;
}
__device__ __forceinline__ float wsum(float v){
  #pragma unroll
  for (int m = 32; m >= 1; m >>= 1) v += __shfl_xor(v, m, 64);
  return v;
}
// pack 4 f32 -> 4 fp8 e4m3 (OCP on gfx950) in one u32
__device__ __forceinline__ uint32_t pk4_fp8(float a, float b, float c, float d){
  int w = __builtin_amdgcn_cvt_pk_fp8_f32(a, b, 0, false);
  w = __builtin_amdgcn_cvt_pk_fp8_f32(c, d, w, true);
  return (uint32_t)w;
}

// ---- prologue: pipelined fp8 fragment pack + row inv-sums -----------------
// pbf8: [b][chunk=2S+c][s=8][lane][8fp8]; byte j: exp(x[n][32s+8(l>>4)+j]),
//       n = 8*(rho>>2)+4c+(rho&3), rho=lane&15   (A-frag, row-interleaved)
// xbf8: [b][S][dt=16][lane][8fp8]; byte j: x[8*(l>>4)+j][16dt+(lane&15)] (B-frag)
// invs: 1/sum_d exp(x[n][d])  (f32, per row)
__global__ __launch_bounds__(256, 2) void k_prep6(const float* __restrict__ x,
                                                  uint2* __restrict__ pbf8,
                                                  uint2* __restrict__ xbf8,
                                                  float* __restrict__ invs){
  __shared__ float xs[2][32 * PSTR];               // 2 x 33.3 KB
  const int b = blockIdx.y;
  const int Sbase = blockIdx.x * TPB;
  const int tid = threadIdx.x;
  const int wave = tid >> 6, lane = tid & 63;
  const float* xb = x + (size_t)b * NN * DD;

  // stage S-tile into buffer: each wave its 8 rows, width-16 gload_lds
  auto stage = [&](int S, int buf){
    #pragma unroll
    for (int r = 0; r < 8; ++r){
      int row = wave * 8 + r;
      const float* gp = xb + ((size_t)S * 32 + row) * DD + lane * 4;
      float* lp = &xs[buf][row * PSTR];
      __builtin_amdgcn_global_load_lds(
          (const __attribute__((address_space(1))) unsigned int*)gp,
          (__attribute__((address_space(3))) unsigned int*)lp, 16, 0, 0);
    }
  };

  stage(Sbase, 0);
  for (int it = 0; it < TPB; ++it){
    const int S = Sbase + it;
    const int cur = it & 1;
    asm volatile("s_waitcnt vmcnt(0)" ::: "memory");
    __builtin_amdgcn_sched_barrier(0);
    __syncthreads();                               // xs[cur] ready (all waves)
    if (it + 1 < TPB) stage(S + 1, cur ^ 1);

    // ---- row sums: row = 8w + (lane&7), col-block = lane>>3 --------------
    {
      int row = 8 * wave + (lane & 7);
      const float* pr = &xs[cur][row * PSTR + (lane >> 3) * 32];
      float a = 0.f;
      #pragma unroll
      for (int i = 0; i < 8; ++i){
        float4 v = *(const float4*)&pr[4 * i];
        a += __expf(v.x) + __expf(v.y) + __expf(v.z) + __expf(v.w);
      }
      a += __shfl_xor(a, 8, 64);
      a += __shfl_xor(a, 16, 64);
      a += __shfl_xor(a, 32, 64);
      if (lane < 8) invs[(size_t)b * NN + S * 32 + 8 * wave + lane] = frcp(a);
    }

    // ---- pbf pack: 4 (c,s) tasks per wave --------------------------------
    #pragma unroll
    for (int i = 0; i < 4; ++i){
      int p = wave * 4 + i; int c = p >> 3, s = p & 7;
      int rho = lane & 15;
      int n = 8 * (rho >> 2) + 4 * c + (rho & 3);
      int d = 32 * s + 8 * (lane >> 4);
      float4 v0 = *(const float4*)&xs[cur][n * PSTR + d];
      float4 v1 = *(const float4*)&xs[cur][n * PSTR + d + 4];
      uint2 o;
      o.x = pk4_fp8(__expf(v0.x), __expf(v0.y), __expf(v0.z), __expf(v0.w));
      o.y = pk4_fp8(__expf(v1.x), __expf(v1.y), __expf(v1.z), __expf(v1.w));
      pbf8[(((size_t)b * 1024 + (size_t)S * 2 + c) * 8 + s) * 64 + lane] = o;
    }
    // ---- xbf pack: 4 dt tasks per wave -----------------------------------
    #pragma unroll
    for (int i = 0; i < 4; ++i){
      int dt = wave * 4 + i;
      int col = dt * 16 + (lane & 15);
      int g2 = lane >> 4;
      float v[8];
      #pragma unroll
      for (int j = 0; j < 8; ++j) v[j] = xs[cur][(8 * g2 + j) * PSTR + col];
      uint2 o;
      o.x = pk4_fp8(v[0], v[1], v[2], v[3]);
      o.y = pk4_fp8(v[4], v[5], v[6], v[7]);
      xbf8[(((size_t)b * 512 + S) * 16 + dt) * 64 + lane] = o;
    }
    __syncthreads();                               // all done reading xs[cur]
  }
}

// ---- init: lq residual (log_softmax + LOG256) as fp8 B-frags + logpi ------
__global__ __launch_bounds__(256) void k_init6(const float* __restrict__ slot_logits,
                                               const float* __restrict__ mix,
                                               uint8_t* __restrict__ lqf8,
                                               float* __restrict__ logpi){
  int w    = blockIdx.x * 4 + (threadIdx.x >> 6);   // b*K + k
  int lane = threadIdx.x & 63;
  int b = w >> 4, k = w & 15;
  const float4* sl = (const float4*)(slot_logits + (size_t)k * DD);
  float4 t = sl[lane];
  float m = wmax(fmaxf(fmaxf(t.x, t.y), fmaxf(t.z, t.w)));
  float s = wsum(__expf(t.x-m) + __expf(t.y-m) + __expf(t.z-m) + __expf(t.w-m));
  float L = m + __logf(s) - LOG256;                 // residual offset
  int d0 = lane * 4;
  int ss = d0 >> 5;
  int l2 = (((d0 & 31) >> 3) << 4) + k;
  int jb = d0 & 7;                                  // 0 or 4
  uint32_t wv = pk4_fp8(t.x - L, t.y - L, t.z - L, t.w - L);
  *(uint32_t*)(lqf8 + ((((size_t)b * 8 + ss) * 64 + l2) * 8 + jb)) = wv;
  if (lane == 0) logpi[w] = __logf(mix[k] + EPSV);
}

// ---- fused EM iteration via fp8 MFMA --------------------------------------
__global__ __launch_bounds__(256, 2) void k_em6(const uint2* __restrict__ pbf8,
                                                const uint2* __restrict__ xbf8,
                                                const uint2* __restrict__ lqf8,
                                                const float* __restrict__ logpi,
                                                const float* __restrict__ invs,
                                                float* __restrict__ pnum,
                                                float* __restrict__ ppi){
  __shared__ float sred[KK * DD];
  __shared__ float spi2[16];
  const int b = blockIdx.y, g = blockIdx.x;          // g: 0..63
  const int tid = threadIdx.x;
  const int wave = tid >> 6, lane = tid & 63;

  i64v lq8[8];
  {
    const uint2* p = lqf8 + (size_t)b * 8 * 64 + lane;
    #pragma unroll
    for (int s = 0; s < 8; ++s){ uint2 t = p[s * 64]; lq8[s] = *(i64v*)&t; }
  }
  const float lpik = logpi[b * KK + (lane & 15)];

  f32x4 acc[16];
  #pragma unroll
  for (int dt = 0; dt < 16; ++dt) acc[dt] = (f32x4){0.f, 0.f, 0.f, 0.f};
  float piacc = 0.f;

  const int S0 = (g * 4 + wave) * 2;
  #pragma unroll
  for (int ssi = 0; ssi < 2; ++ssi){
    const int S = S0 + ssi;
    const uint2* pb = pbf8 + (((size_t)b * 1024 + (size_t)S * 2) * 8) * 64 + lane;
    const uint2* xr = xbf8 + (((size_t)b * 512 + S) * 16) * 64 + lane;

    uint2 pa[16];
    #pragma unroll
    for (int i = 0; i < 16; ++i) pa[i] = pb[(size_t)i * 64];   // [c*8+s]

    float ivs[8];
    {
      const float* ib = invs + (size_t)b * NN + S * 32 + 8 * (lane >> 4);
      #pragma unroll
      for (int j = 0; j < 8; ++j) ivs[j] = ib[j];
    }

    float ga[8];
    #pragma unroll
    for (int c = 0; c < 2; ++c){
      f32x4 lc = (f32x4){0.f, 0.f, 0.f, 0.f};
      #pragma unroll
      for (int s = 0; s < 8; ++s){
        i64v a = *(i64v*)&pa[c * 8 + s];
        lc = __builtin_amdgcn_mfma_f32_16x16x32_fp8_fp8(a, lq8[s], lc, 0, 0, 0);
      }
      #pragma unroll
      for (int r2 = 0; r2 < 4; ++r2){
        float lg = fmaf(lc[r2], ivs[c * 4 + r2], lpik);
        float mx = lg;
        #pragma unroll
        for (int m = 1; m <= 8; m <<= 1) mx = fmaxf(mx, __shfl_xor(mx, m, 64));
        float e = __expf(lg - mx);
        float s2 = e;
        #pragma unroll
        for (int m = 1; m <= 8; m <<= 1) s2 += __shfl_xor(s2, m, 64);
        ga[c * 4 + r2] = e * frcp(s2);
      }
    }
    // gamma -> fp8 A-frag; use DEQUANTIZED gamma for pi (consistency)
    uint2 gp;
    gp.x = pk4_fp8(ga[0], ga[1], ga[2], ga[3]);
    gp.y = pk4_fp8(ga[4], ga[5], ga[6], ga[7]);
    piacc += __builtin_amdgcn_cvt_f32_fp8((int)gp.x, 0)
           + __builtin_amdgcn_cvt_f32_fp8((int)gp.x, 1)
           + __builtin_amdgcn_cvt_f32_fp8((int)gp.x, 2)
           + __builtin_amdgcn_cvt_f32_fp8((int)gp.x, 3)
           + __builtin_amdgcn_cvt_f32_fp8((int)gp.y, 0)
           + __builtin_amdgcn_cvt_f32_fp8((int)gp.y, 1)
           + __builtin_amdgcn_cvt_f32_fp8((int)gp.y, 2)
           + __builtin_amdgcn_cvt_f32_fp8((int)gp.y, 3);
    i64v gA = *(i64v*)&gp;
    #pragma unroll
    for (int dt = 0; dt < 16; ++dt){
      uint2 xv = xr[(size_t)dt * 64];
      acc[dt] = __builtin_amdgcn_mfma_f32_16x16x32_fp8_fp8(gA, *(i64v*)&xv,
                                                           acc[dt], 0, 0, 0);
    }
  }

  // epilogue: cross-wave reduce (identical to verified r11 structure)
  float pk = piacc;
  pk += __shfl_xor(pk, 16, 64);
  pk += __shfl_xor(pk, 32, 64);
  __syncthreads();
  if (wave == 0){
    #pragma unroll
    for (int dt = 0; dt < 16; ++dt)
      #pragma unroll
      for (int r2 = 0; r2 < 4; ++r2)
        sred[(4 * (lane >> 4) + r2) * DD + dt * 16 + (lane & 15)] = acc[dt][r2];
    if (lane < 16) spi2[lane] = pk;
  }
  __syncthreads();
  for (int w = 1; w < 4; ++w){
    if (wave == w){
      #pragma unroll
      for (int dt = 0; dt < 16; ++dt)
        #pragma unroll
        for (int r2 = 0; r2 < 4; ++r2)
          sred[(4 * (lane >> 4) + r2) * DD + dt * 16 + (lane & 15)] += acc[dt][r2];
      if (lane < 16) spi2[lane] += pk;
    }
    __syncthreads();
  }
  float4* dst4 = (float4*)(pnum + (size_t)(b * 64 + g) * KK * DD);
  const float4* s4 = (const float4*)sred;
  #pragma unroll
  for (int j = 0; j < 4; ++j) dst4[tid + j * 256] = s4[tid + j * 256];
  if (tid < 16) ppi[(size_t)(b * 64 + g) * KK + tid] = spi2[tid];
}

// ---- reduce partials -> theta, lq fp8 frags, log_pi (G=64) ----------------
__global__ __launch_bounds__(64) void k_reduce6(const float* __restrict__ pnum,
                                                const float* __restrict__ ppi,
                                                float* __restrict__ theta,
                                                uint8_t* __restrict__ lqf8,
                                                float* __restrict__ logpi){
  const int G = 64;
  int w = blockIdx.x;              // b*K + k
  int lane = threadIdx.x;
  int b = w >> 4, k = w & 15;
  float4 sum = make_float4(0.f, 0.f, 0.f, 0.f);
  const float4* base = (const float4*)pnum + ((size_t)b * G * KK + k) * (DD/4) + lane;
  #pragma unroll 4
  for (int g = 0; g < G; ++g){
    float4 t = base[(size_t)g * KK * (DD/4)];
    sum.x += t.x; sum.y += t.y; sum.z += t.z; sum.w += t.w;
  }
  float ps = 0.f;
  for (int g = lane; g < G; g += 64) ps += ppi[((size_t)b * G + g) * KK + k];
  ps = wsum(ps);
  float inv = frcp(ps + EPSV);
  float4 th = make_float4(sum.x * inv, sum.y * inv, sum.z * inv, sum.w * inv);
  ((float4*)(theta + (size_t)w * DD))[lane] = th;
  float m = wmax(fmaxf(fmaxf(th.x, th.y), fmaxf(th.z, th.w)));
  float s = wsum(__expf(th.x-m) + __expf(th.y-m) + __expf(th.z-m) + __expf(th.w-m));
  float L = m + __logf(s) - LOG256;
  int d0 = lane * 4;
  int ss = d0 >> 5;
  int l2 = (((d0 & 31) >> 3) << 4) + k;
  int jb = d0 & 7;
  uint32_t wv = pk4_fp8(th.x - L, th.y - L, th.z - L, th.w - L);
  *(uint32_t*)(lqf8 + ((((size_t)b * 8 + ss) * 64 + l2) * 8 + jb)) = wv;
  if (lane == 0) logpi[w] = __logf(ps * (1.0f / NN) + EPSV);
}

// ---- final: gumbel (threefry partitionable XOR-fold, VERIFIED) ------------
__device__ __forceinline__ uint32_t rotl32(uint32_t x, int r){ return (x << r) | (x >> (32 - r)); }
__device__ __forceinline__ void tf2x32(uint32_t k0, uint32_t k1, uint32_t c0, uint32_t c1,
                                       uint32_t& o0, uint32_t& o1){
  uint32_t ks0 = k0, ks1 = k1, ks2 = 0x1BD11BDAu ^ k0 ^ k1;
  uint32_t x0 = c0 + ks0, x1 = c1 + ks1;
  #define RND(r) { x0 += x1; x1 = rotl32(x1, r); x1 ^= x0; }
  RND(13) RND(15) RND(26) RND(6)   x0 += ks1; x1 += ks2 + 1u;
  RND(17) RND(29) RND(16) RND(24)  x0 += ks2; x1 += ks0 + 2u;
  RND(13) RND(15) RND(26) RND(6)   x0 += ks0; x1 += ks1 + 3u;
  RND(17) RND(29) RND(16) RND(24)  x0 += ks1; x1 += ks2 + 4u;
  RND(13) RND(15) RND(26) RND(6)   x0 += ks2; x1 += ks0 + 5u;
  #undef RND
  o0 = x0; o1 = x1;
}

__global__ __launch_bounds__(256) void k_final(const float* __restrict__ theta,
                                               float* __restrict__ out){
  int w    = blockIdx.x * 4 + (threadIdx.x >> 6);
  int lane = threadIdx.x & 63;
  float4 th = ((const float4*)(theta + (size_t)w * DD))[lane];
  int i0 = w * DD + lane * 4;
  float gv[4];
  #pragma unroll
  for (int j = 0; j < 4; ++j){
    uint32_t i = (uint32_t)(i0 + j);
    uint32_t o0, o1;
    tf2x32(0u, 1u, 0u, i, o0, o1);
    uint32_t bits = o0 ^ o1;
    float f = __uint_as_float((bits >> 9) | 0x3f800000u) - 1.0f;
    const float TINY = 1.17549435e-38f;
    float u = fmaxf(f + TINY, TINY);
    gv[j] = -logf(-logf(u));
  }
  float4 y = make_float4(th.x + gv[0], th.y + gv[1], th.z + gv[2], th.w + gv[3]);
  float m = wmax(fmaxf(fmaxf(y.x, y.y), fmaxf(y.z, y.w)));
  float4 e = make_float4(__expf(y.x-m), __expf(y.y-m), __expf(y.z-m), __expf(y.w-m));
  float s = wsum(e.x + e.y + e.z + e.w);
  float inv = 1.0f / s;
  ((float4*)(out + (size_t)w * DD))[lane] =
      make_float4(e.x*inv, e.y*inv, e.z*inv, e.w*inv);
}

__global__ __launch_bounds__(256) void k_fill(float* __restrict__ out, float v){
  out[blockIdx.x * 256 + threadIdx.x] = v;
}

extern "C" void kernel_launch(void* const* d_in, const int* in_sizes, int n_in,
                              void* d_out, int out_size, void* d_ws, size_t ws_size,
                              hipStream_t stream){
  const float* x    = (const float*)d_in[0];
  const float* sl   = (const float*)d_in[1];
  const float* mix  = (const float*)d_in[2];
  float* out = (float*)d_out;
  char* ws = (char*)d_ws;

  const size_t SZ_PBF  = 33554432ull;              // 8*1024*8*64*8
  const size_t SZ_XBF  = 33554432ull;              // 8*512*16*64*8
  const size_t SZ_LQF  = 32768ull;                 // 8*8*64*8
  const size_t SZ_INV  = (size_t)BN*NN*4;          // 524288
  const size_t SZ_TH   = (size_t)BN*KK*DD*4;       // 131072
  const size_t SZ_LP   = 512ull;
  const size_t SZ_PNUM = (size_t)BN*64*KK*DD*4;    // 33554432
  const size_t SZ_PPI  = (size_t)BN*64*KK*4;       // 32768
  size_t need = SZ_PBF + SZ_XBF + SZ_LQF + SZ_INV + SZ_TH + SZ_LP + SZ_PNUM + SZ_PPI;

  if (ws_size < need){
    k_fill<<<(BN*KK*DD)/256, 256, 0, stream>>>(out, -9.0f);   // diag: ws too small
    return;
  }
  size_t o = 0;
  uint2*   pbf8  = (uint2*)(ws + o);     o += SZ_PBF;
  uint2*   xbf8  = (uint2*)(ws + o);     o += SZ_XBF;
  uint8_t* lqf8  = (uint8_t*)(ws + o);   o += SZ_LQF;
  float*   invs  = (float*)(ws + o);     o += SZ_INV;
  float*   theta = (float*)(ws + o);     o += SZ_TH;
  float*   logpi = (float*)(ws + o);     o += SZ_LP;
  float*   pnum  = (float*)(ws + o);     o += SZ_PNUM;
  float*   ppi   = (float*)(ws + o);

  k_prep6<<<dim3(512 / TPB, BN), 256, 0, stream>>>(x, pbf8, xbf8, invs);
  k_init6<<<(BN*KK)/4, 256, 0, stream>>>(sl, mix, lqf8, logpi);
  for (int it = 0; it < NITER; ++it){
    k_em6    <<<dim3(64, BN), 256, 0, stream>>>(pbf8, xbf8, (const uint2*)lqf8,
                                                logpi, invs, pnum, ppi);
    k_reduce6<<<BN*KK, 64, 0, stream>>>(pnum, ppi, theta, lqf8, logpi);
  }
  k_final<<<(BN*KK)/4, 256, 0, stream>>>(theta, out);
}

// Round 13
// 157.400 us; speedup vs baseline: 3.8986x; 1.0176x over previous
//
#include <hip/hip_runtime.h>
#include <cstdint>
#include <cstddef>

#define BN 8
#define NN 16384
#define DD 256
#define KK 16
#define NITER 5
#define EPSV 1e-8f
#define LOG256 5.545177444479562f
#define PSTR 260   // LDS row stride (words); 1040 B, 16B-aligned
#define TPB 8      // S-tiles per k_prep block
#define GG 32      // split-N partial count per batch

typedef float f32x4 __attribute__((ext_vector_type(4)));
typedef long  i64v;

__device__ __forceinline__ float frcp(float x){ return __builtin_amdgcn_rcpf(x); }
__device__ __forceinline__ float wmax(float v){
  #pragma unroll
  for (int m = 32; m >= 1; m >>= 1) v = fmaxf(v, __shfl_xor(v, m, 64));
  return v;
}
__device__ __forceinline__ float wsum(float v){
  #pragma unroll
  for (int m = 32; m >= 1; m >>= 1) v += __shfl_xor(v, m, 64);
  return v;
}
// pack 4 f32 -> 4 fp8 e4m3 (OCP on gfx950) in one u32
__device__ __forceinline__ uint32_t pk4_fp8(float a, float b, float c, float d){
  int w = __builtin_amdgcn_cvt_pk_fp8_f32(a, b, 0, false);
  w = __builtin_amdgcn_cvt_pk_fp8_f32(c, d, w, true);
  return (uint32_t)w;
}
__device__ __forceinline__ uint32_t f2bf(float f){   // RNE f32->bf16
  uint32_t u = __float_as_uint(f);
  return (u + 0x7fffu + ((u >> 16) & 1u)) >> 16;
}
__device__ __forceinline__ uint32_t pk2bf(float a, float b){
  return f2bf(a) | (f2bf(b) << 16);
}
__device__ __forceinline__ float bf2f(uint32_t h){ return __uint_as_float(h << 16); }

// ---- prologue: pipelined fp8 fragment pack + row inv-sums -----------------
// pbf8: [b][chunk=2S+c][s=8][lane][8fp8]; byte j: exp(x[n][32s+8(l>>4)+j]),
//       n = 8*(rho>>2)+4c+(rho&3), rho=lane&15   (A-frag, row-interleaved)
// xbf8: [b][S][dt=16][lane][8fp8]; byte j: x[8*(l>>4)+j][16dt+(lane&15)] (B-frag)
// invs: 1/sum_d exp(x[n][d])  (f32, per row)
__global__ __launch_bounds__(256, 2) void k_prep6(const float* __restrict__ x,
                                                  uint2* __restrict__ pbf8,
                                                  uint2* __restrict__ xbf8,
                                                  float* __restrict__ invs){
  __shared__ float xs[2][32 * PSTR];               // 2 x 33.3 KB
  const int b = blockIdx.y;
  const int Sbase = blockIdx.x * TPB;
  const int tid = threadIdx.x;
  const int wave = tid >> 6, lane = tid & 63;
  const float* xb = x + (size_t)b * NN * DD;

  auto stage = [&](int S, int buf){
    #pragma unroll
    for (int r = 0; r < 8; ++r){
      int row = wave * 8 + r;
      const float* gp = xb + ((size_t)S * 32 + row) * DD + lane * 4;
      float* lp = &xs[buf][row * PSTR];
      __builtin_amdgcn_global_load_lds(
          (const __attribute__((address_space(1))) unsigned int*)gp,
          (__attribute__((address_space(3))) unsigned int*)lp, 16, 0, 0);
    }
  };

  stage(Sbase, 0);
  for (int it = 0; it < TPB; ++it){
    const int S = Sbase + it;
    const int cur = it & 1;
    asm volatile("s_waitcnt vmcnt(0)" ::: "memory");
    __builtin_amdgcn_sched_barrier(0);
    __syncthreads();                               // xs[cur] ready (all waves)
    if (it + 1 < TPB) stage(S + 1, cur ^ 1);

    // ---- row sums --------------------------------------------------------
    {
      int row = 8 * wave + (lane & 7);
      const float* pr = &xs[cur][row * PSTR + (lane >> 3) * 32];
      float a = 0.f;
      #pragma unroll
      for (int i = 0; i < 8; ++i){
        float4 v = *(const float4*)&pr[4 * i];
        a += __expf(v.x) + __expf(v.y) + __expf(v.z) + __expf(v.w);
      }
      a += __shfl_xor(a, 8, 64);
      a += __shfl_xor(a, 16, 64);
      a += __shfl_xor(a, 32, 64);
      if (lane < 8) invs[(size_t)b * NN + S * 32 + 8 * wave + lane] = frcp(a);
    }

    // ---- pbf pack: 4 (c,s) tasks per wave --------------------------------
    #pragma unroll
    for (int i = 0; i < 4; ++i){
      int p = wave * 4 + i; int c = p >> 3, s = p & 7;
      int rho = lane & 15;
      int n = 8 * (rho >> 2) + 4 * c + (rho & 3);
      int d = 32 * s + 8 * (lane >> 4);
      float4 v0 = *(const float4*)&xs[cur][n * PSTR + d];
      float4 v1 = *(const float4*)&xs[cur][n * PSTR + d + 4];
      uint2 o;
      o.x = pk4_fp8(__expf(v0.x), __expf(v0.y), __expf(v0.z), __expf(v0.w));
      o.y = pk4_fp8(__expf(v1.x), __expf(v1.y), __expf(v1.z), __expf(v1.w));
      pbf8[(((size_t)b * 1024 + (size_t)S * 2 + c) * 8 + s) * 64 + lane] = o;
    }
    // ---- xbf pack: 4 dt tasks per wave -----------------------------------
    #pragma unroll
    for (int i = 0; i < 4; ++i){
      int dt = wave * 4 + i;
      int col = dt * 16 + (lane & 15);
      int g2 = lane >> 4;
      float v[8];
      #pragma unroll
      for (int j = 0; j < 8; ++j) v[j] = xs[cur][(8 * g2 + j) * PSTR + col];
      uint2 o;
      o.x = pk4_fp8(v[0], v[1], v[2], v[3]);
      o.y = pk4_fp8(v[4], v[5], v[6], v[7]);
      xbf8[(((size_t)b * 512 + S) * 16 + dt) * 64 + lane] = o;
    }
    __syncthreads();                               // all done reading xs[cur]
  }
}

// ---- init: lq residual (log_softmax + LOG256) as fp8 B-frags + logpi ------
__global__ __launch_bounds__(256) void k_init6(const float* __restrict__ slot_logits,
                                               const float* __restrict__ mix,
                                               uint8_t* __restrict__ lqf8,
                                               float* __restrict__ logpi){
  int w    = blockIdx.x * 4 + (threadIdx.x >> 6);   // b*K + k
  int lane = threadIdx.x & 63;
  int b = w >> 4, k = w & 15;
  const float4* sl = (const float4*)(slot_logits + (size_t)k * DD);
  float4 t = sl[lane];
  float m = wmax(fmaxf(fmaxf(t.x, t.y), fmaxf(t.z, t.w)));
  float s = wsum(__expf(t.x-m) + __expf(t.y-m) + __expf(t.z-m) + __expf(t.w-m));
  float L = m + __logf(s) - LOG256;                 // residual offset
  int d0 = lane * 4;
  int ss = d0 >> 5;
  int l2 = (((d0 & 31) >> 3) << 4) + k;
  int jb = d0 & 7;                                  // 0 or 4
  uint32_t wv = pk4_fp8(t.x - L, t.y - L, t.z - L, t.w - L);
  *(uint32_t*)(lqf8 + ((((size_t)b * 8 + ss) * 64 + l2) * 8 + jb)) = wv;
  if (lane == 0) logpi[w] = __logf(mix[k] + EPSV);
}

// ---- fused EM iteration via fp8 MFMA; bf16 partials -----------------------
__global__ __launch_bounds__(256, 2) void k_em6(const uint2* __restrict__ pbf8,
                                                const uint2* __restrict__ xbf8,
                                                const uint2* __restrict__ lqf8,
                                                const float* __restrict__ logpi,
                                                const float* __restrict__ invs,
                                                uint16_t* __restrict__ pnumb,
                                                float* __restrict__ ppi){
  __shared__ float sred[KK * DD];
  __shared__ float spi2[16];
  const int b = blockIdx.y, g = blockIdx.x;          // g: 0..GG-1
  const int tid = threadIdx.x;
  const int wave = tid >> 6, lane = tid & 63;

  i64v lq8[8];
  {
    const uint2* p = lqf8 + (size_t)b * 8 * 64 + lane;
    #pragma unroll
    for (int s = 0; s < 8; ++s){ uint2 t = p[s * 64]; lq8[s] = *(i64v*)&t; }
  }
  const float lpik = logpi[b * KK + (lane & 15)];

  f32x4 acc[16];
  #pragma unroll
  for (int dt = 0; dt < 16; ++dt) acc[dt] = (f32x4){0.f, 0.f, 0.f, 0.f};
  float piacc = 0.f;

  const int S0 = (g * 4 + wave) * 4;                 // 4 supersteps per wave
  #pragma unroll
  for (int ssi = 0; ssi < 4; ++ssi){
    const int S = S0 + ssi;
    const uint2* pb = pbf8 + (((size_t)b * 1024 + (size_t)S * 2) * 8) * 64 + lane;
    const uint2* xr = xbf8 + (((size_t)b * 512 + S) * 16) * 64 + lane;

    uint2 pa[16];
    #pragma unroll
    for (int i = 0; i < 16; ++i) pa[i] = pb[(size_t)i * 64];   // [c*8+s]

    float ivs[8];
    {
      const float* ib = invs + (size_t)b * NN + S * 32 + 8 * (lane >> 4);
      #pragma unroll
      for (int j = 0; j < 8; ++j) ivs[j] = ib[j];
    }

    float ga[8];
    #pragma unroll
    for (int c = 0; c < 2; ++c){
      f32x4 lc = (f32x4){0.f, 0.f, 0.f, 0.f};
      #pragma unroll
      for (int s = 0; s < 8; ++s){
        i64v a = *(i64v*)&pa[c * 8 + s];
        lc = __builtin_amdgcn_mfma_f32_16x16x32_fp8_fp8(a, lq8[s], lc, 0, 0, 0);
      }
      #pragma unroll
      for (int r2 = 0; r2 < 4; ++r2){
        float lg = fmaf(lc[r2], ivs[c * 4 + r2], lpik);
        float mx = lg;
        #pragma unroll
        for (int m = 1; m <= 8; m <<= 1) mx = fmaxf(mx, __shfl_xor(mx, m, 64));
        float e = __expf(lg - mx);
        float s2 = e;
        #pragma unroll
        for (int m = 1; m <= 8; m <<= 1) s2 += __shfl_xor(s2, m, 64);
        ga[c * 4 + r2] = e * frcp(s2);
      }
    }
    // gamma -> fp8 A-frag; DEQUANTIZED gamma for pi (consistency)
    uint2 gp;
    gp.x = pk4_fp8(ga[0], ga[1], ga[2], ga[3]);
    gp.y = pk4_fp8(ga[4], ga[5], ga[6], ga[7]);
    piacc += __builtin_amdgcn_cvt_f32_fp8((int)gp.x, 0)
           + __builtin_amdgcn_cvt_f32_fp8((int)gp.x, 1)
           + __builtin_amdgcn_cvt_f32_fp8((int)gp.x, 2)
           + __builtin_amdgcn_cvt_f32_fp8((int)gp.x, 3)
           + __builtin_amdgcn_cvt_f32_fp8((int)gp.y, 0)
           + __builtin_amdgcn_cvt_f32_fp8((int)gp.y, 1)
           + __builtin_amdgcn_cvt_f32_fp8((int)gp.y, 2)
           + __builtin_amdgcn_cvt_f32_fp8((int)gp.y, 3);
    i64v gA = *(i64v*)&gp;
    #pragma unroll
    for (int dt = 0; dt < 16; ++dt){
      uint2 xv = xr[(size_t)dt * 64];
      acc[dt] = __builtin_amdgcn_mfma_f32_16x16x32_fp8_fp8(gA, *(i64v*)&xv,
                                                           acc[dt], 0, 0, 0);
    }
  }

  // epilogue: cross-wave reduce (r11-verified structure)
  float pk = piacc;
  pk += __shfl_xor(pk, 16, 64);
  pk += __shfl_xor(pk, 32, 64);
  __syncthreads();
  if (wave == 0){
    #pragma unroll
    for (int dt = 0; dt < 16; ++dt)
      #pragma unroll
      for (int r2 = 0; r2 < 4; ++r2)
        sred[(4 * (lane >> 4) + r2) * DD + dt * 16 + (lane & 15)] = acc[dt][r2];
    if (lane < 16) spi2[lane] = pk;
  }
  __syncthreads();
  for (int w = 1; w < 4; ++w){
    if (wave == w){
      #pragma unroll
      for (int dt = 0; dt < 16; ++dt)
        #pragma unroll
        for (int r2 = 0; r2 < 4; ++r2)
          sred[(4 * (lane >> 4) + r2) * DD + dt * 16 + (lane & 15)] += acc[dt][r2];
      if (lane < 16) spi2[lane] += pk;
    }
    __syncthreads();
  }
  // bf16 partial write: thread t packs elems (2t, 2t+1) + j*512
  uint32_t* dst = (uint32_t*)(pnumb + (size_t)(b * GG + g) * KK * DD);
  #pragma unroll
  for (int j = 0; j < 8; ++j){
    float a = sred[tid * 2 + j * 512];
    float c = sred[tid * 2 + 1 + j * 512];
    dst[tid + j * 256] = pk2bf(a, c);
  }
  if (tid < 16) ppi[(size_t)(b * GG + g) * KK + tid] = spi2[tid];
}

// ---- reduce partials (bf16) -> theta, lq fp8 frags, log_pi ----------------
__global__ __launch_bounds__(64) void k_reduce6(const uint16_t* __restrict__ pnumb,
                                                const float* __restrict__ ppi,
                                                float* __restrict__ theta,
                                                uint8_t* __restrict__ lqf8,
                                                float* __restrict__ logpi){
  int w = blockIdx.x;              // b*K + k
  int lane = threadIdx.x;
  int b = w >> 4, k = w & 15;
  float4 sum = make_float4(0.f, 0.f, 0.f, 0.f);
  #pragma unroll 4
  for (int g = 0; g < GG; ++g){
    const uint2* p = (const uint2*)(pnumb +
        ((size_t)(b * GG + g) * KK + k) * DD + lane * 4);
    uint2 v = *p;
    sum.x += bf2f(v.x & 0xffffu); sum.y += bf2f(v.x >> 16);
    sum.z += bf2f(v.y & 0xffffu); sum.w += bf2f(v.y >> 16);
  }
  float ps = 0.f;
  for (int g = lane; g < GG; g += 64) ps += ppi[((size_t)b * GG + g) * KK + k];
  ps = wsum(ps);
  float inv = frcp(ps + EPSV);
  float4 th = make_float4(sum.x * inv, sum.y * inv, sum.z * inv, sum.w * inv);
  ((float4*)(theta + (size_t)w * DD))[lane] = th;
  float m = wmax(fmaxf(fmaxf(th.x, th.y), fmaxf(th.z, th.w)));
  float s = wsum(__expf(th.x-m) + __expf(th.y-m) + __expf(th.z-m) + __expf(th.w-m));
  float L = m + __logf(s) - LOG256;
  int d0 = lane * 4;
  int ss = d0 >> 5;
  int l2 = (((d0 & 31) >> 3) << 4) + k;
  int jb = d0 & 7;
  uint32_t wv = pk4_fp8(th.x - L, th.y - L, th.z - L, th.w - L);
  *(uint32_t*)(lqf8 + ((((size_t)b * 8 + ss) * 64 + l2) * 8 + jb)) = wv;
  if (lane == 0) logpi[w] = __logf(ps * (1.0f / NN) + EPSV);
}

// ---- final: gumbel (threefry partitionable XOR-fold, VERIFIED) ------------
__device__ __forceinline__ uint32_t rotl32(uint32_t x, int r){ return (x << r) | (x >> (32 - r)); }
__device__ __forceinline__ void tf2x32(uint32_t k0, uint32_t k1, uint32_t c0, uint32_t c1,
                                       uint32_t& o0, uint32_t& o1){
  uint32_t ks0 = k0, ks1 = k1, ks2 = 0x1BD11BDAu ^ k0 ^ k1;
  uint32_t x0 = c0 + ks0, x1 = c1 + ks1;
  #define RND(r) { x0 += x1; x1 = rotl32(x1, r); x1 ^= x0; }
  RND(13) RND(15) RND(26) RND(6)   x0 += ks1; x1 += ks2 + 1u;
  RND(17) RND(29) RND(16) RND(24)  x0 += ks2; x1 += ks0 + 2u;
  RND(13) RND(15) RND(26) RND(6)   x0 += ks0; x1 += ks1 + 3u;
  RND(17) RND(29) RND(16) RND(24)  x0 += ks1; x1 += ks2 + 4u;
  RND(13) RND(15) RND(26) RND(6)   x0 += ks2; x1 += ks0 + 5u;
  #undef RND
  o0 = x0; o1 = x1;
}

__global__ __launch_bounds__(256) void k_final(const float* __restrict__ theta,
                                               float* __restrict__ out){
  int w    = blockIdx.x * 4 + (threadIdx.x >> 6);
  int lane = threadIdx.x & 63;
  float4 th = ((const float4*)(theta + (size_t)w * DD))[lane];
  int i0 = w * DD + lane * 4;
  float gv[4];
  #pragma unroll
  for (int j = 0; j < 4; ++j){
    uint32_t i = (uint32_t)(i0 + j);
    uint32_t o0, o1;
    tf2x32(0u, 1u, 0u, i, o0, o1);
    uint32_t bits = o0 ^ o1;
    float f = __uint_as_float((bits >> 9) | 0x3f800000u) - 1.0f;
    const float TINY = 1.17549435e-38f;
    float u = fmaxf(f + TINY, TINY);
    gv[j] = -logf(-logf(u));
  }
  float4 y = make_float4(th.x + gv[0], th.y + gv[1], th.z + gv[2], th.w + gv[3]);
  float m = wmax(fmaxf(fmaxf(y.x, y.y), fmaxf(y.z, y.w)));
  float4 e = make_float4(__expf(y.x-m), __expf(y.y-m), __expf(y.z-m), __expf(y.w-m));
  float s = wsum(e.x + e.y + e.z + e.w);
  float inv = 1.0f / s;
  ((float4*)(out + (size_t)w * DD))[lane] =
      make_float4(e.x*inv, e.y*inv, e.z*inv, e.w*inv);
}

__global__ __launch_bounds__(256) void k_fill(float* __restrict__ out, float v){
  out[blockIdx.x * 256 + threadIdx.x] = v;
}

extern "C" void kernel_launch(void* const* d_in, const int* in_sizes, int n_in,
                              void* d_out, int out_size, void* d_ws, size_t ws_size,
                              hipStream_t stream){
  const float* x    = (const float*)d_in[0];
  const float* sl   = (const float*)d_in[1];
  const float* mix  = (const float*)d_in[2];
  float* out = (float*)d_out;
  char* ws = (char*)d_ws;

  const size_t SZ_PBF  = 33554432ull;              // 8*1024*8*64*8
  const size_t SZ_XBF  = 33554432ull;              // 8*512*16*64*8
  const size_t SZ_LQF  = 32768ull;                 // 8*8*64*8
  const size_t SZ_INV  = (size_t)BN*NN*4;          // 524288
  const size_t SZ_TH   = (size_t)BN*KK*DD*4;       // 131072
  const size_t SZ_LP   = 512ull;
  const size_t SZ_PNUM = (size_t)BN*GG*KK*DD*2;    // 2 MB (bf16)
  const size_t SZ_PPI  = (size_t)BN*GG*KK*4;       // 16384
  size_t need = SZ_PBF + SZ_XBF + SZ_LQF + SZ_INV + SZ_TH + SZ_LP + SZ_PNUM + SZ_PPI;

  if (ws_size < need){
    k_fill<<<(BN*KK*DD)/256, 256, 0, stream>>>(out, -9.0f);   // diag: ws too small
    return;
  }
  size_t o = 0;
  uint2*    pbf8  = (uint2*)(ws + o);     o += SZ_PBF;
  uint2*    xbf8  = (uint2*)(ws + o);     o += SZ_XBF;
  uint8_t*  lqf8  = (uint8_t*)(ws + o);   o += SZ_LQF;
  float*    invs  = (float*)(ws + o);     o += SZ_INV;
  float*    theta = (float*)(ws + o);     o += SZ_TH;
  float*    logpi = (float*)(ws + o);     o += SZ_LP;
  uint16_t* pnumb = (uint16_t*)(ws + o);  o += SZ_PNUM;
  float*    ppi   = (float*)(ws + o);

  k_prep6<<<dim3(512 / TPB, BN), 256, 0, stream>>>(x, pbf8, xbf8, invs);
  k_init6<<<(BN*KK)/4, 256, 0, stream>>>(sl, mix, lqf8, logpi);
  for (int it = 0; it < NITER; ++it){
    k_em6    <<<dim3(GG, BN), 256, 0, stream>>>(pbf8, xbf8, (const uint2*)lqf8,
                                                logpi, invs, pnumb, ppi);
    k_reduce6<<<BN*KK, 64, 0, stream>>>(pnumb, ppi, theta, lqf8, logpi);
  }
  k_final<<<(BN*KK)/4, 256, 0, stream>>>(theta, out);
}